// Round 1
// baseline (6228.185 us; speedup 1.0000x reference)
//
#include <hip/hip_runtime.h>

#define EPSN 1e-6f
#define EPSM 1e-5f

// ---------------- inv L2-norm over channel dim (c=256) ----------------
// positions: 4 batches * 1024 spatial = 4096; 64 positions per block,
// 4 channel-chunks of 64 per position.
__global__ __launch_bounds__(256) void invnorm_k(const float* __restrict__ f,
                                                 float* __restrict__ inv)
{
    int pbase = blockIdx.x * 64;
    int pp = threadIdx.x & 63;
    int cc = threadIdx.x >> 6;          // 0..3
    int pos = pbase + pp;               // b*1024 + ij
    int b = pos >> 10, ij = pos & 1023;
    const float* fp = f + (size_t)(b * 256) * 1024 + ij;
    float s = 0.f;
    #pragma unroll 8
    for (int k = 0; k < 64; ++k) {
        float v = fp[(size_t)(cc * 64 + k) * 1024];
        s += v * v;
    }
    __shared__ float red[4][64];
    red[cc][pp] = s;
    __syncthreads();
    if (cc == 0) {
        float t = red[0][pp] + red[1][pp] + red[2][pp] + red[3][pp];
        inv[pos] = rsqrtf(t + EPSN);
    }
}

// ---------------- correlation GEMM: out[i,j] = sum_c A[c,i]*B[c,j] ----------------
// per batch: M=N=1024, K=256. 64x64 tile per 256-thread block, 4x4 micro-tile.
// epilogue: relu + x*rsqrt(x^2+1e-6)
__global__ __launch_bounds__(256) void corr_k(const float* __restrict__ fa,
                                              const float* __restrict__ fb,
                                              const float* __restrict__ invA,
                                              const float* __restrict__ invB,
                                              float* __restrict__ corr)
{
    __shared__ float As[16][68];
    __shared__ float Bs[16][68];
    int b = blockIdx.z;
    int i0 = blockIdx.y * 64, j0 = blockIdx.x * 64;
    int tid = threadIdx.x;
    int tx = tid & 15, ty = tid >> 4;
    const float* fab = fa + (size_t)b * 256 * 1024;
    const float* fbb = fb + (size_t)b * 256 * 1024;
    const float* ia = invA + b * 1024 + i0;
    const float* ib = invB + b * 1024 + j0;
    float acc[4][4] = {};
    for (int kc = 0; kc < 256; kc += 16) {
        #pragma unroll
        for (int l = 0; l < 4; ++l) {
            int idx = tid + l * 256;
            int r = idx >> 6, cix = idx & 63;
            As[r][cix] = fab[(size_t)(kc + r) * 1024 + i0 + cix] * ia[cix];
            Bs[r][cix] = fbb[(size_t)(kc + r) * 1024 + j0 + cix] * ib[cix];
        }
        __syncthreads();
        #pragma unroll
        for (int k = 0; k < 16; ++k) {
            float4 av = *(const float4*)&As[k][ty * 4];
            float4 bv = *(const float4*)&Bs[k][tx * 4];
            float a[4] = {av.x, av.y, av.z, av.w};
            float bq[4] = {bv.x, bv.y, bv.z, bv.w};
            #pragma unroll
            for (int ii = 0; ii < 4; ++ii)
                #pragma unroll
                for (int jj = 0; jj < 4; ++jj)
                    acc[ii][jj] += a[ii] * bq[jj];
        }
        __syncthreads();
    }
    float* cb = corr + ((size_t)b << 20);
    #pragma unroll
    for (int ii = 0; ii < 4; ++ii) {
        float4 o; float v;
        v = fmaxf(acc[ii][0], 0.f); o.x = v * rsqrtf(v * v + EPSN);
        v = fmaxf(acc[ii][1], 0.f); o.y = v * rsqrtf(v * v + EPSN);
        v = fmaxf(acc[ii][2], 0.f); o.z = v * rsqrtf(v * v + EPSN);
        v = fmaxf(acc[ii][3], 0.f); o.w = v * rsqrtf(v * v + EPSN);
        *(float4*)&cb[(size_t)(i0 + ty * 4 + ii) * 1024 + j0 + tx * 4] = o;
    }
}

// ---------------- mutual matching ----------------
// c viewed per batch as [1024(i=f1f2)][1024(j=f3f4)], all values >= 0.
__global__ __launch_bounds__(256) void rowmax_k(const float* __restrict__ c,
                                                float* __restrict__ maxR)
{
    int b = blockIdx.y, i = blockIdx.x, tid = threadIdx.x;
    const float* row = c + ((size_t)b << 20) + ((size_t)i << 10);
    float m = fmaxf(fmaxf(row[tid], row[tid + 256]), fmaxf(row[tid + 512], row[tid + 768]));
    #pragma unroll
    for (int off = 32; off; off >>= 1) m = fmaxf(m, __shfl_down(m, off, 64));
    __shared__ float sred[4];
    if ((tid & 63) == 0) sred[tid >> 6] = m;
    __syncthreads();
    if (tid == 0)
        maxR[b * 1024 + i] = fmaxf(fmaxf(sred[0], sred[1]), fmaxf(sred[2], sred[3]));
}

__global__ __launch_bounds__(256) void colmax_k(const float* __restrict__ c,
                                                float* __restrict__ maxC)
{
    int j = blockIdx.x * 256 + threadIdx.x;
    int r0 = blockIdx.y * 128;
    int b = blockIdx.z;
    const float* cb = c + ((size_t)b << 20);
    float m = 0.f;
    for (int r = 0; r < 128; ++r) m = fmaxf(m, cb[(size_t)(r0 + r) * 1024 + j]);
    // values are non-negative -> int compare == float compare
    atomicMax((int*)&maxC[b * 1024 + j], __float_as_int(m));
}

__global__ __launch_bounds__(256) void mmapply_k(float* __restrict__ c,
                                                 const float* __restrict__ maxR,
                                                 const float* __restrict__ maxC)
{
    int e4 = blockIdx.x * 256 + threadIdx.x;  // float4 index, 1M total
    int e = e4 * 4;
    int b = e >> 20, i = (e >> 10) & 1023, j0 = e & 1023;
    float4 v = ((float4*)c)[e4];
    float ra = 1.f / (maxR[b * 1024 + i] + EPSM);
    float4 mb = ((const float4*)maxC)[(b * 1024 + j0) >> 2];
    float4 o;
    o.x = v.x * v.x * v.x * ra / (mb.x + EPSM);
    o.y = v.y * v.y * v.y * ra / (mb.y + EPSM);
    o.z = v.z * v.z * v.z * ra / (mb.z + EPSM);
    o.w = v.w * v.w * v.w * ra / (mb.w + EPSM);
    ((float4*)c)[e4] = o;
}

// ---------------- weight kernel-axis permute: w'[..,i,j,k,l] = w[..,k,l,i,j] ----------------
__global__ void permw_k(const float* __restrict__ src, float* __restrict__ dst, int n)
{
    int idx = blockIdx.x * 256 + threadIdx.x;
    if (idx >= n) return;
    int base = idx / 81, t = idx % 81;
    int d1 = t / 27, d2 = (t / 9) % 3, d3 = (t / 3) % 3, d4 = t % 3;
    int tp = d3 * 27 + d4 * 9 + d1 * 3 + d2;
    dst[base * 81 + t] = src[base * 81 + tp];
}

// ---------------- 4D conv (3^4 taps, pad 1), relu epilogue, optional accumulate ----------------
// x: [CI][32][32][32][32] (one batch), w: [CO][CI][81], y: [CO][32^4]
// block = one (f1,f2); full 32x32 (f3,f4) plane; thread: 4 consecutive f4 points.
template <int CI, int CO, bool ADD>
__global__ __launch_bounds__(256) void conv4d_k(const float* __restrict__ x,
                                                const float* __restrict__ w,
                                                const float* __restrict__ bias,
                                                float* __restrict__ y)
{
    constexpr int GS = (3 * CO + 3) & ~3;   // padded (d4,co) group stride
    __shared__ float tile[9 * 34 * 36];     // [s1*3+s2][34 rows][36 cols (34 used)]
    __shared__ float wl[CI * 27 * GS];

    int tid = threadIdx.x;
    int f1 = blockIdx.x >> 5, f2 = blockIdx.x & 31;

    // stage weights: global [(co*CI+ci)*81 + d1*27+d2*9+d3*3+d4]
    //   -> lds [(ci*27 + d123)*GS + d4*CO + co]
    for (int idx = tid; idx < CO * CI * 81; idx += 256) {
        int co = idx / (CI * 81);
        int r = idx - co * CI * 81;
        int ci = r / 81;
        int t81 = r - ci * 81;
        int d4 = t81 % 3;
        int d123 = t81 / 3;
        wl[(ci * 27 + d123) * GS + d4 * CO + co] = w[idx];
    }

    int x0 = (tid & 7) * 4;   // f4 group (4 consecutive)
    int yy = tid >> 3;        // f3 row (0..31)

    float acc[CO][4];
    #pragma unroll
    for (int co = 0; co < CO; ++co) {
        float bv = bias[co];
        #pragma unroll
        for (int p = 0; p < 4; ++p) acc[co][p] = bv;
    }

    for (int ci = 0; ci < CI; ++ci) {
        __syncthreads();   // previous tile fully consumed
        const float* xc = x + (size_t)ci * 1048576;
        for (int idx = tid; idx < 9 * 34 * 34; idx += 256) {
            int slab = idx / 1156;
            int rem = idx - slab * 1156;
            int r = rem / 34;
            int cix = rem - r * 34;
            int s1 = slab / 3, s2 = slab - s1 * 3;
            int g1 = f1 + s1 - 1, g2 = f2 + s2 - 1, g3 = r - 1, g4 = cix - 1;
            float v = 0.f;
            if (((unsigned)g1 < 32u) & ((unsigned)g2 < 32u) &
                ((unsigned)g3 < 32u) & ((unsigned)g4 < 32u))
                v = xc[((size_t)(g1 * 32 + g2) << 10) + g3 * 32 + g4];
            tile[slab * 1224 + r * 36 + cix] = v;
        }
        __syncthreads();

        #pragma unroll
        for (int d1 = 0; d1 < 3; ++d1)
        #pragma unroll
        for (int d2 = 0; d2 < 3; ++d2) {
            const float* slabp = &tile[(d1 * 3 + d2) * 1224];
            #pragma unroll
            for (int d3 = 0; d3 < 3; ++d3) {
                const float* rowp = &slabp[(yy + d3) * 36 + x0];
                float4 t4 = *(const float4*)rowp;
                float2 t2 = *(const float2*)(rowp + 4);
                float xs[6] = {t4.x, t4.y, t4.z, t4.w, t2.x, t2.y};
                const float* wg = &wl[(ci * 27 + d1 * 9 + d2 * 3 + d3) * GS];
                float wv[GS];
                #pragma unroll
                for (int q = 0; q < GS / 4; ++q) {
                    float4 wq = ((const float4*)wg)[q];
                    wv[q * 4 + 0] = wq.x; wv[q * 4 + 1] = wq.y;
                    wv[q * 4 + 2] = wq.z; wv[q * 4 + 3] = wq.w;
                }
                #pragma unroll
                for (int d4 = 0; d4 < 3; ++d4)
                #pragma unroll
                for (int co = 0; co < CO; ++co) {
                    float wf = wv[d4 * CO + co];
                    #pragma unroll
                    for (int p = 0; p < 4; ++p)
                        acc[co][p] += xs[p + d4] * wf;
                }
            }
        }
    }

    size_t obase = ((size_t)(f1 * 32 + f2) << 10) + yy * 32 + x0;
    #pragma unroll
    for (int co = 0; co < CO; ++co) {
        float4 o;
        o.x = fmaxf(acc[co][0], 0.f);
        o.y = fmaxf(acc[co][1], 0.f);
        o.z = fmaxf(acc[co][2], 0.f);
        o.w = fmaxf(acc[co][3], 0.f);
        float* yp = y + (size_t)co * 1048576 + obase;
        if (ADD) {
            float4 prev = *(const float4*)yp;
            o.x += prev.x; o.y += prev.y; o.z += prev.z; o.w += prev.w;
        }
        *(float4*)yp = o;
    }
}

extern "C" void kernel_launch(void* const* d_in, const int* in_sizes, int n_in,
                              void* d_out, int out_size, void* d_ws, size_t ws_size,
                              hipStream_t stream)
{
    (void)in_sizes; (void)n_in; (void)out_size; (void)ws_size;
    const float* fA = (const float*)d_in[0];
    const float* fB = (const float*)d_in[1];
    const float* w1 = (const float*)d_in[2];
    const float* b1 = (const float*)d_in[3];
    const float* w2 = (const float*)d_in[4];
    const float* b2 = (const float*)d_in[5];
    const float* w3 = (const float*)d_in[6];
    const float* b3 = (const float*)d_in[7];
    float* out = (float*)d_out;
    float* ws = (float*)d_ws;

    size_t o = 0;
    float* invA = ws + o; o += 4096;
    float* invB = ws + o; o += 4096;
    float* maxR = ws + o; o += 4096;
    float* maxC = ws + o; o += 4096;
    float* w1p  = ws + o; o += 832;
    float* w2p  = ws + o; o += 8112;
    float* w3p  = ws + o; o += 832;
    float* corr = ws + o; o += 4194304;   // [4][1024][1024]
    float* t1   = ws + o; o += 10485760;  // [10][32^4]
    float* t2   = ws + o; o += 10485760;  // [10][32^4]

    invnorm_k<<<64, 256, 0, stream>>>(fA, invA);
    invnorm_k<<<64, 256, 0, stream>>>(fB, invB);
    corr_k<<<dim3(16, 16, 4), 256, 0, stream>>>(fA, fB, invA, invB, corr);

    // mutual matching #1 (in place on corr)
    rowmax_k<<<dim3(1024, 4), 256, 0, stream>>>(corr, maxR);
    hipMemsetAsync(maxC, 0, 4096 * sizeof(float), stream);
    colmax_k<<<dim3(4, 8, 4), 256, 0, stream>>>(corr, maxC);
    mmapply_k<<<4096, 256, 0, stream>>>(corr, maxR, maxC);

    // permuted weights for symmetric branch
    permw_k<<<4, 256, 0, stream>>>(w1, w1p, 810);
    permw_k<<<32, 256, 0, stream>>>(w2, w2p, 8100);
    permw_k<<<4, 256, 0, stream>>>(w3, w3p, 810);

    for (int b = 0; b < 4; ++b) {
        const float* xb = corr + (size_t)b * 1048576;
        float* ob = out + (size_t)b * 1048576;
        conv4d_k<1, 10, false><<<1024, 256, 0, stream>>>(xb, w1, b1, t1);
        conv4d_k<10, 10, false><<<1024, 256, 0, stream>>>(t1, w2, b2, t2);
        conv4d_k<10, 1, false><<<1024, 256, 0, stream>>>(t2, w3, b3, ob);
        conv4d_k<1, 10, false><<<1024, 256, 0, stream>>>(xb, w1p, b1, t1);
        conv4d_k<10, 10, false><<<1024, 256, 0, stream>>>(t1, w2p, b2, t2);
        conv4d_k<10, 1, true ><<<1024, 256, 0, stream>>>(t2, w3p, b3, ob);
    }

    // mutual matching #2 (in place on out)
    rowmax_k<<<dim3(1024, 4), 256, 0, stream>>>(out, maxR);
    hipMemsetAsync(maxC, 0, 4096 * sizeof(float), stream);
    colmax_k<<<dim3(4, 8, 4), 256, 0, stream>>>(out, maxC);
    mmapply_k<<<4096, 256, 0, stream>>>(out, maxR, maxC);
}

// Round 2
// 4159.550 us; speedup vs baseline: 1.4973x; 1.4973x over previous
//
#include <hip/hip_runtime.h>

#define EPSN 1e-6f
#define EPSM 1e-5f

// ---------------- inv L2-norm over channel dim (c=256) ----------------
__global__ __launch_bounds__(256) void invnorm_k(const float* __restrict__ f,
                                                 float* __restrict__ inv)
{
    int pbase = blockIdx.x * 64;
    int pp = threadIdx.x & 63;
    int cc = threadIdx.x >> 6;          // 0..3
    int pos = pbase + pp;               // b*1024 + ij
    int b = pos >> 10, ij = pos & 1023;
    const float* fp = f + (size_t)(b * 256) * 1024 + ij;
    float s = 0.f;
    #pragma unroll 8
    for (int k = 0; k < 64; ++k) {
        float v = fp[(size_t)(cc * 64 + k) * 1024];
        s += v * v;
    }
    __shared__ float red[4][64];
    red[cc][pp] = s;
    __syncthreads();
    if (cc == 0) {
        float t = red[0][pp] + red[1][pp] + red[2][pp] + red[3][pp];
        inv[pos] = rsqrtf(t + EPSN);
    }
}

// ---------------- correlation GEMM + relu + softsign ----------------
__global__ __launch_bounds__(256) void corr_k(const float* __restrict__ fa,
                                              const float* __restrict__ fb,
                                              const float* __restrict__ invA,
                                              const float* __restrict__ invB,
                                              float* __restrict__ corr)
{
    __shared__ float As[16][68];
    __shared__ float Bs[16][68];
    int b = blockIdx.z;
    int i0 = blockIdx.y * 64, j0 = blockIdx.x * 64;
    int tid = threadIdx.x;
    int tx = tid & 15, ty = tid >> 4;
    const float* fab = fa + (size_t)b * 256 * 1024;
    const float* fbb = fb + (size_t)b * 256 * 1024;
    const float* ia = invA + b * 1024 + i0;
    const float* ib = invB + b * 1024 + j0;
    float acc[4][4] = {};
    for (int kc = 0; kc < 256; kc += 16) {
        #pragma unroll
        for (int l = 0; l < 4; ++l) {
            int idx = tid + l * 256;
            int r = idx >> 6, cix = idx & 63;
            As[r][cix] = fab[(size_t)(kc + r) * 1024 + i0 + cix] * ia[cix];
            Bs[r][cix] = fbb[(size_t)(kc + r) * 1024 + j0 + cix] * ib[cix];
        }
        __syncthreads();
        #pragma unroll
        for (int k = 0; k < 16; ++k) {
            float4 av = *(const float4*)&As[k][ty * 4];
            float4 bv = *(const float4*)&Bs[k][tx * 4];
            float a[4] = {av.x, av.y, av.z, av.w};
            float bq[4] = {bv.x, bv.y, bv.z, bv.w};
            #pragma unroll
            for (int ii = 0; ii < 4; ++ii)
                #pragma unroll
                for (int jj = 0; jj < 4; ++jj)
                    acc[ii][jj] += a[ii] * bq[jj];
        }
        __syncthreads();
    }
    float* cb = corr + ((size_t)b << 20);
    #pragma unroll
    for (int ii = 0; ii < 4; ++ii) {
        float4 o; float v;
        v = fmaxf(acc[ii][0], 0.f); o.x = v * rsqrtf(v * v + EPSN);
        v = fmaxf(acc[ii][1], 0.f); o.y = v * rsqrtf(v * v + EPSN);
        v = fmaxf(acc[ii][2], 0.f); o.z = v * rsqrtf(v * v + EPSN);
        v = fmaxf(acc[ii][3], 0.f); o.w = v * rsqrtf(v * v + EPSN);
        *(float4*)&cb[(size_t)(i0 + ty * 4 + ii) * 1024 + j0 + tx * 4] = o;
    }
}

// ---------------- mutual matching ----------------
__global__ __launch_bounds__(256) void rowmax_k(const float* __restrict__ c,
                                                float* __restrict__ maxR)
{
    int b = blockIdx.y, i = blockIdx.x, tid = threadIdx.x;
    const float* row = c + ((size_t)b << 20) + ((size_t)i << 10);
    float m = fmaxf(fmaxf(row[tid], row[tid + 256]), fmaxf(row[tid + 512], row[tid + 768]));
    #pragma unroll
    for (int off = 32; off; off >>= 1) m = fmaxf(m, __shfl_down(m, off, 64));
    __shared__ float sred[4];
    if ((tid & 63) == 0) sred[tid >> 6] = m;
    __syncthreads();
    if (tid == 0)
        maxR[b * 1024 + i] = fmaxf(fmaxf(sred[0], sred[1]), fmaxf(sred[2], sred[3]));
}

__global__ __launch_bounds__(256) void colmax_k(const float* __restrict__ c,
                                                float* __restrict__ maxC)
{
    int j = blockIdx.x * 256 + threadIdx.x;
    int r0 = blockIdx.y * 128;
    int b = blockIdx.z;
    const float* cb = c + ((size_t)b << 20);
    float m = 0.f;
    for (int r = 0; r < 128; ++r) m = fmaxf(m, cb[(size_t)(r0 + r) * 1024 + j]);
    atomicMax((int*)&maxC[b * 1024 + j], __float_as_int(m));
}

__global__ __launch_bounds__(256) void mmapply_k(float* __restrict__ c,
                                                 const float* __restrict__ maxR,
                                                 const float* __restrict__ maxC)
{
    int e4 = blockIdx.x * 256 + threadIdx.x;
    int e = e4 * 4;
    int b = e >> 20, i = (e >> 10) & 1023, j0 = e & 1023;
    float4 v = ((float4*)c)[e4];
    float ra = 1.f / (maxR[b * 1024 + i] + EPSM);
    float4 mb = ((const float4*)maxC)[(b * 1024 + j0) >> 2];
    float4 o;
    o.x = v.x * v.x * v.x * ra / (mb.x + EPSM);
    o.y = v.y * v.y * v.y * ra / (mb.y + EPSM);
    o.z = v.z * v.z * v.z * ra / (mb.z + EPSM);
    o.w = v.w * v.w * v.w * ra / (mb.w + EPSM);
    ((float4*)c)[e4] = o;
}

// ---------------- weight pack: [CO][CI][81] -> [CI][27(d123)][WS] ----------------
// slot = d4*CO + co; tap t = d123*3 + d4; perm: src tap (d1,d2,d3,d4) <- (d3,d4,d1,d2)
template <int CI, int CO>
__global__ void packw_k(const float* __restrict__ w, float* __restrict__ dst, int perm)
{
    constexpr int WS = (3 * CO + 3) & ~3;
    int idx = blockIdx.x * 256 + threadIdx.x;
    if (idx >= CI * 27 * WS) return;
    int ci = idx / (27 * WS);
    int rem = idx - ci * 27 * WS;
    int d123 = rem / WS;
    int slot = rem - d123 * WS;
    float v = 0.f;
    if (slot < 3 * CO) {
        int d4 = slot / CO, co = slot - d4 * CO;
        int t = d123 * 3 + d4;
        int d1 = t / 27, r2 = t % 27;
        int d2 = r2 / 9, r3 = r2 % 9;
        int d3 = r3 / 3, dd4 = r3 % 3;
        int st = perm ? (d3 * 27 + dd4 * 9 + d1 * 3 + d2) : t;
        v = w[(co * CI + ci) * 81 + st];
    }
    dst[idx] = v;
}

// ---------------- 4D conv (3^4 taps, pad 1), relu epilogue, optional accumulate ----
// x: [CI][32^4] (one batch), wp: [CI][27][WS] packed (slot=d4*CO+co), y: [CO][32^4]
// block = one (f1,f2); thread = (f3 row, 4 consecutive f4). LDS: 3 slabs (d2 halo)
// staged per (ci,d1). Weights read via uniform (SGPR) loads.
template <int CI, int CO, bool ADD>
__global__ __launch_bounds__(256, 4) void conv4d_k(const float* __restrict__ x,
                                                   const float* __restrict__ wp,
                                                   const float* __restrict__ bias,
                                                   float* __restrict__ y)
{
    constexpr int WS = (3 * CO + 3) & ~3;
    __shared__ float tile[3 * 34 * 36];   // [s2][34 rows][36 cols (34 used)]

    int tid = threadIdx.x;
    int f1 = blockIdx.x >> 5, f2 = blockIdx.x & 31;
    int x0 = (tid & 7) * 4;   // f4 group
    int yy = tid >> 3;        // f3 row

    float acc[CO][4];
    #pragma unroll
    for (int co = 0; co < CO; ++co) {
        float bv = bias[co];
        acc[co][0] = bv; acc[co][1] = bv; acc[co][2] = bv; acc[co][3] = bv;
    }

    #pragma unroll 1
    for (int ci = 0; ci < CI; ++ci) {
        const float* xc = x + ((size_t)ci << 20);
        const float* wci = wp + ci * 27 * WS;
        #pragma unroll 1
        for (int d1 = 0; d1 < 3; ++d1) {
            int g1 = f1 + d1 - 1;
            bool g1ok = (unsigned)g1 < 32u;
            __syncthreads();   // previous phase fully consumed
            // stage 3 slabs (s2=0..2) of plane g1: 3*34*34 = 3468 elements
            #pragma unroll 1
            for (int e = tid; e < 3468; e += 256) {
                int s2 = e / 1156, rem = e - s2 * 1156;
                int r = rem / 34, c = rem - r * 34;
                int g2 = f2 + s2 - 1, g3 = r - 1, g4 = c - 1;
                bool ok = g1ok & ((unsigned)g2 < 32u) &
                          ((unsigned)g3 < 32u) & ((unsigned)g4 < 32u);
                float v = 0.f;
                if (ok)
                    v = xc[((size_t)((g1 << 5) + g2) << 10) + (g3 << 5) + g4];
                tile[s2 * 1224 + r * 36 + c] = v;
            }
            __syncthreads();

            #pragma unroll 1
            for (int d2 = 0; d2 < 3; ++d2) {
                const float* slabp = tile + d2 * 1224;
                const float* wg0 = wci + (d1 * 9 + d2 * 3) * WS;
                #pragma unroll
                for (int d3 = 0; d3 < 3; ++d3) {
                    const float* rowp = slabp + (yy + d3) * 36 + x0;
                    float4 a = *(const float4*)rowp;
                    float2 b2v = *(const float2*)(rowp + 4);
                    float xs[6] = {a.x, a.y, a.z, a.w, b2v.x, b2v.y};
                    const float* wg = wg0 + d3 * WS;   // uniform -> s_load
                    #pragma unroll
                    for (int d4 = 0; d4 < 3; ++d4)
                        #pragma unroll
                        for (int co = 0; co < CO; ++co) {
                            float wf = wg[d4 * CO + co];
                            #pragma unroll
                            for (int p = 0; p < 4; ++p)
                                acc[co][p] = fmaf(xs[p + d4], wf, acc[co][p]);
                        }
                }
            }
        }
    }

    size_t obase = ((size_t)(f1 * 32 + f2) << 10) + yy * 32 + x0;
    #pragma unroll
    for (int co = 0; co < CO; ++co) {
        float4 o;
        o.x = fmaxf(acc[co][0], 0.f);
        o.y = fmaxf(acc[co][1], 0.f);
        o.z = fmaxf(acc[co][2], 0.f);
        o.w = fmaxf(acc[co][3], 0.f);
        float* yp = y + ((size_t)co << 20) + obase;
        if (ADD) {
            float4 prev = *(const float4*)yp;
            o.x += prev.x; o.y += prev.y; o.z += prev.z; o.w += prev.w;
        }
        *(float4*)yp = o;
    }
}

extern "C" void kernel_launch(void* const* d_in, const int* in_sizes, int n_in,
                              void* d_out, int out_size, void* d_ws, size_t ws_size,
                              hipStream_t stream)
{
    (void)in_sizes; (void)n_in; (void)out_size; (void)ws_size;
    const float* fA = (const float*)d_in[0];
    const float* fB = (const float*)d_in[1];
    const float* w1 = (const float*)d_in[2];
    const float* b1 = (const float*)d_in[3];
    const float* w2 = (const float*)d_in[4];
    const float* b2 = (const float*)d_in[5];
    const float* w3 = (const float*)d_in[6];
    const float* b3 = (const float*)d_in[7];
    float* out = (float*)d_out;
    float* ws = (float*)d_ws;

    size_t o = 0;
    float* invA = ws + o; o += 4096;
    float* invB = ws + o; o += 4096;
    float* maxR = ws + o; o += 4096;
    float* maxC = ws + o; o += 4096;
    float* pL1A = ws + o; o += 864;      // [1][27][32]
    float* pL1B = ws + o; o += 864;
    float* pL2A = ws + o; o += 8640;     // [10][27][32]
    float* pL2B = ws + o; o += 8640;
    float* pL3A = ws + o; o += 1080;     // [10][27][4]
    float* pL3B = ws + o; o += 1080;
    float* corr = ws + o; o += 4194304;  // [4][1024][1024]
    float* t1   = ws + o; o += 10485760; // [10][32^4]
    float* t2   = ws + o; o += 10485760; // [10][32^4]

    invnorm_k<<<64, 256, 0, stream>>>(fA, invA);
    invnorm_k<<<64, 256, 0, stream>>>(fB, invB);
    corr_k<<<dim3(16, 16, 4), 256, 0, stream>>>(fA, fB, invA, invB, corr);

    // mutual matching #1 (in place on corr)
    rowmax_k<<<dim3(1024, 4), 256, 0, stream>>>(corr, maxR);
    hipMemsetAsync(maxC, 0, 4096 * sizeof(float), stream);
    colmax_k<<<dim3(4, 8, 4), 256, 0, stream>>>(corr, maxC);
    mmapply_k<<<4096, 256, 0, stream>>>(corr, maxR, maxC);

    // packed weights (A = normal, B = kernel-axis-permuted for symmetric branch)
    packw_k<1, 10><<<4, 256, 0, stream>>>(w1, pL1A, 0);
    packw_k<1, 10><<<4, 256, 0, stream>>>(w1, pL1B, 1);
    packw_k<10, 10><<<34, 256, 0, stream>>>(w2, pL2A, 0);
    packw_k<10, 10><<<34, 256, 0, stream>>>(w2, pL2B, 1);
    packw_k<10, 1><<<5, 256, 0, stream>>>(w3, pL3A, 0);
    packw_k<10, 1><<<5, 256, 0, stream>>>(w3, pL3B, 1);

    for (int b = 0; b < 4; ++b) {
        const float* xb = corr + (size_t)b * 1048576;
        float* ob = out + (size_t)b * 1048576;
        conv4d_k<1, 10, false><<<1024, 256, 0, stream>>>(xb, pL1A, b1, t1);
        conv4d_k<10, 10, false><<<1024, 256, 0, stream>>>(t1, pL2A, b2, t2);
        conv4d_k<10, 1, false><<<1024, 256, 0, stream>>>(t2, pL3A, b3, ob);
        conv4d_k<1, 10, false><<<1024, 256, 0, stream>>>(xb, pL1B, b1, t1);
        conv4d_k<10, 10, false><<<1024, 256, 0, stream>>>(t1, pL2B, b2, t2);
        conv4d_k<10, 1, true ><<<1024, 256, 0, stream>>>(t2, pL3B, b3, ob);
    }

    // mutual matching #2 (in place on out)
    rowmax_k<<<dim3(1024, 4), 256, 0, stream>>>(out, maxR);
    hipMemsetAsync(maxC, 0, 4096 * sizeof(float), stream);
    colmax_k<<<dim3(4, 8, 4), 256, 0, stream>>>(out, maxC);
    mmapply_k<<<4096, 256, 0, stream>>>(out, maxR, maxC);
}

// Round 3
// 2620.679 us; speedup vs baseline: 2.3766x; 1.5872x over previous
//
#include <hip/hip_runtime.h>

#define EPSN 1e-6f
#define EPSM 1e-5f

// ---------------- inv L2-norm over channel dim (c=256) ----------------
__global__ __launch_bounds__(256) void invnorm_k(const float* __restrict__ f,
                                                 float* __restrict__ inv)
{
    int pbase = blockIdx.x * 64;
    int pp = threadIdx.x & 63;
    int cc = threadIdx.x >> 6;          // 0..3
    int pos = pbase + pp;               // b*1024 + ij
    int b = pos >> 10, ij = pos & 1023;
    const float* fp = f + (size_t)(b * 256) * 1024 + ij;
    float s = 0.f;
    #pragma unroll 8
    for (int k = 0; k < 64; ++k) {
        float v = fp[(size_t)(cc * 64 + k) * 1024];
        s += v * v;
    }
    __shared__ float red[4][64];
    red[cc][pp] = s;
    __syncthreads();
    if (cc == 0) {
        float t = red[0][pp] + red[1][pp] + red[2][pp] + red[3][pp];
        inv[pos] = rsqrtf(t + EPSN);
    }
}

// ---------------- correlation GEMM + relu + softsign ----------------
__global__ __launch_bounds__(256) void corr_k(const float* __restrict__ fa,
                                              const float* __restrict__ fb,
                                              const float* __restrict__ invA,
                                              const float* __restrict__ invB,
                                              float* __restrict__ corr)
{
    __shared__ float As[16][68];
    __shared__ float Bs[16][68];
    int b = blockIdx.z;
    int i0 = blockIdx.y * 64, j0 = blockIdx.x * 64;
    int tid = threadIdx.x;
    int tx = tid & 15, ty = tid >> 4;
    const float* fab = fa + (size_t)b * 256 * 1024;
    const float* fbb = fb + (size_t)b * 256 * 1024;
    const float* ia = invA + b * 1024 + i0;
    const float* ib = invB + b * 1024 + j0;
    float acc[4][4] = {};
    for (int kc = 0; kc < 256; kc += 16) {
        #pragma unroll
        for (int l = 0; l < 4; ++l) {
            int idx = tid + l * 256;
            int r = idx >> 6, cix = idx & 63;
            As[r][cix] = fab[(size_t)(kc + r) * 1024 + i0 + cix] * ia[cix];
            Bs[r][cix] = fbb[(size_t)(kc + r) * 1024 + j0 + cix] * ib[cix];
        }
        __syncthreads();
        #pragma unroll
        for (int k = 0; k < 16; ++k) {
            float4 av = *(const float4*)&As[k][ty * 4];
            float4 bv = *(const float4*)&Bs[k][tx * 4];
            float a[4] = {av.x, av.y, av.z, av.w};
            float bq[4] = {bv.x, bv.y, bv.z, bv.w};
            #pragma unroll
            for (int ii = 0; ii < 4; ++ii)
                #pragma unroll
                for (int jj = 0; jj < 4; ++jj)
                    acc[ii][jj] += a[ii] * bq[jj];
        }
        __syncthreads();
    }
    float* cb = corr + ((size_t)b << 20);
    #pragma unroll
    for (int ii = 0; ii < 4; ++ii) {
        float4 o; float v;
        v = fmaxf(acc[ii][0], 0.f); o.x = v * rsqrtf(v * v + EPSN);
        v = fmaxf(acc[ii][1], 0.f); o.y = v * rsqrtf(v * v + EPSN);
        v = fmaxf(acc[ii][2], 0.f); o.z = v * rsqrtf(v * v + EPSN);
        v = fmaxf(acc[ii][3], 0.f); o.w = v * rsqrtf(v * v + EPSN);
        *(float4*)&cb[(size_t)(i0 + ty * 4 + ii) * 1024 + j0 + tx * 4] = o;
    }
}

// ---------------- mutual matching ----------------
__global__ __launch_bounds__(256) void rowmax_k(const float* __restrict__ c,
                                                float* __restrict__ maxR)
{
    int b = blockIdx.y, i = blockIdx.x, tid = threadIdx.x;
    const float* row = c + ((size_t)b << 20) + ((size_t)i << 10);
    float m = fmaxf(fmaxf(row[tid], row[tid + 256]), fmaxf(row[tid + 512], row[tid + 768]));
    #pragma unroll
    for (int off = 32; off; off >>= 1) m = fmaxf(m, __shfl_down(m, off, 64));
    __shared__ float sred[4];
    if ((tid & 63) == 0) sred[tid >> 6] = m;
    __syncthreads();
    if (tid == 0)
        maxR[b * 1024 + i] = fmaxf(fmaxf(sred[0], sred[1]), fmaxf(sred[2], sred[3]));
}

__global__ __launch_bounds__(256) void colmax_k(const float* __restrict__ c,
                                                float* __restrict__ maxC)
{
    int j = blockIdx.x * 256 + threadIdx.x;
    int r0 = blockIdx.y * 128;
    int b = blockIdx.z;
    const float* cb = c + ((size_t)b << 20);
    float m = 0.f;
    for (int r = 0; r < 128; ++r) m = fmaxf(m, cb[(size_t)(r0 + r) * 1024 + j]);
    atomicMax((int*)&maxC[b * 1024 + j], __float_as_int(m));
}

__global__ __launch_bounds__(256) void mmapply_k(float* __restrict__ c,
                                                 const float* __restrict__ maxR,
                                                 const float* __restrict__ maxC)
{
    int e4 = blockIdx.x * 256 + threadIdx.x;
    int e = e4 * 4;
    int b = e >> 20, i = (e >> 10) & 1023, j0 = e & 1023;
    float4 v = ((float4*)c)[e4];
    float ra = 1.f / (maxR[b * 1024 + i] + EPSM);
    float4 mb = ((const float4*)maxC)[(b * 1024 + j0) >> 2];
    float4 o;
    o.x = v.x * v.x * v.x * ra / (mb.x + EPSM);
    o.y = v.y * v.y * v.y * ra / (mb.y + EPSM);
    o.z = v.z * v.z * v.z * ra / (mb.z + EPSM);
    o.w = v.w * v.w * v.w * ra / (mb.w + EPSM);
    ((float4*)c)[e4] = o;
}

// ---------------- weight pack: [CO][CI][81] -> [CI][27(d123)][WS] ----------------
// slot = d4*CO + co; perm: src tap (d1,d2,d3,d4) <- (d3,d4,d1,d2)
template <int CI, int CO>
__global__ void packw_k(const float* __restrict__ w, float* __restrict__ dst, int perm)
{
    constexpr int WS = (3 * CO + 3) & ~3;
    int idx = blockIdx.x * 256 + threadIdx.x;
    if (idx >= CI * 27 * WS) return;
    int ci = idx / (27 * WS);
    int rem = idx - ci * 27 * WS;
    int d123 = rem / WS;
    int slot = rem - d123 * WS;
    float v = 0.f;
    if (slot < 3 * CO) {
        int d4 = slot / CO, co = slot - d4 * CO;
        int t = d123 * 3 + d4;
        int d1 = t / 27, r2 = t % 27;
        int d2 = r2 / 9, r3 = r2 % 9;
        int d3 = r3 / 3, dd4 = r3 % 3;
        int st = perm ? (d3 * 27 + dd4 * 9 + d1 * 3 + d2) : t;
        v = w[(co * CI + ci) * 81 + st];
    }
    dst[idx] = v;
}

// ---------------- 4D conv (3^4 taps, pad 1), relu epilogue, optional accumulate ----
// x: [CI][32^4] (one batch), wp: [CI][27][WS] packed (slot=d4*CO+co), y: [CO][32^4]
// block = one (f1,f2); thread = (f3 row yy, 4 consecutive f4 at col-group q).
// LDS tile: 3 slabs (d2 halo) of 34 rows x stride 35 (col c holds g4=c-1; halos
// in dims 3/4 are statically zero -> zero-init once, stage aligned interior only).
// Weights: double-buffered register prefetch (bufA/bufB), one tap ahead.
template <int CI, int CO, bool ADD>
__global__ __launch_bounds__(256, 4) void conv4d_k(const float* __restrict__ x,
                                                   const float* __restrict__ wp,
                                                   const float* __restrict__ bias,
                                                   float* __restrict__ y)
{
    constexpr int WS = (3 * CO + 3) & ~3;
    constexpr int NW4 = WS / 4;
    constexpr int SLAB = 34 * 35;            // 1190
    __shared__ float tile[3 * SLAB];         // 14280 B

    int tid = threadIdx.x;
    int f1 = blockIdx.x >> 5, f2 = blockIdx.x & 31;
    int q = tid & 7, yy = tid >> 3;
    int x0 = q << 2;                          // col of xs[0] (= g4 x0-1)

    // zero whole tile once; halo rows/cols stay zero for the whole kernel
    for (int e = tid; e < 3 * SLAB; e += 256) tile[e] = 0.f;

    float acc[CO][4];
    #pragma unroll
    for (int co = 0; co < CO; ++co) {
        float bv = bias[co];
        acc[co][0] = bv; acc[co][1] = bv; acc[co][2] = bv; acc[co][3] = bv;
    }

    float bufA[WS], bufB[WS];

#define TAP(U, WB, WN, PF) do {                                               \
        constexpr int u_ = (U);                                               \
        const float* rowb_ = &tile[(u_/3)*SLAB + (yy + u_%3)*35 + x0];        \
        float xs_[6];                                                         \
        _Pragma("unroll") for (int j = 0; j < 6; ++j) xs_[j] = rowb_[j];      \
        if (PF) {                                                             \
            _Pragma("unroll") for (int k = 0; k < NW4; ++k)                   \
                *(float4*)&WN[k*4] =                                          \
                    ((const float4*)(wphase + (u_+1)*WS))[k];                 \
        }                                                                     \
        _Pragma("unroll") for (int d4 = 0; d4 < 3; ++d4)                      \
        _Pragma("unroll") for (int co = 0; co < CO; ++co) {                   \
            float wf_ = WB[d4*CO + co];                                       \
            _Pragma("unroll") for (int p = 0; p < 4; ++p)                     \
                acc[co][p] = fmaf(xs_[p + d4], wf_, acc[co][p]);              \
        }                                                                     \
    } while (0)

    #pragma unroll 1
    for (int ci = 0; ci < CI; ++ci) {
        const float* xc = x + ((size_t)ci << 20);
        const float* wci = wp + ci * 27 * WS;
        #pragma unroll 1
        for (int d1 = 0; d1 < 3; ++d1) {
            int g1 = f1 + d1 - 1;
            bool g1ok = (unsigned)g1 < 32u;
            const float* wphase = wci + d1 * 9 * WS;
            __syncthreads();                      // tile consumers done
            // tap-0 weights load (latency hidden under staging)
            #pragma unroll
            for (int k = 0; k < NW4; ++k)
                *(float4*)&bufA[k*4] = ((const float4*)wphase)[k];
            // stage interior: 3 slabs x 32 rows x 8 col-groups = 768 float4
            #pragma unroll
            for (int it = 0; it < 3; ++it) {
                int e = tid + it * 256;
                int s2 = e >> 8, rr = (e >> 3) & 31, qq = e & 7;
                int g2 = f2 + s2 - 1;
                float4 v = {0.f, 0.f, 0.f, 0.f};
                if (g1ok & ((unsigned)g2 < 32u))
                    v = *(const float4*)&x[((size_t)ci << 20) +
                        ((size_t)((g1 << 5) + g2) << 10) + (rr << 5) + (qq << 2)];
                float* t = &tile[s2 * SLAB + (rr + 1) * 35 + 1 + (qq << 2)];
                t[0] = v.x; t[1] = v.y; t[2] = v.z; t[3] = v.w;
            }
            __syncthreads();

            TAP(0, bufA, bufB, true);
            TAP(1, bufB, bufA, true);
            TAP(2, bufA, bufB, true);
            TAP(3, bufB, bufA, true);
            TAP(4, bufA, bufB, true);
            TAP(5, bufB, bufA, true);
            TAP(6, bufA, bufB, true);
            TAP(7, bufB, bufA, true);
            TAP(8, bufA, bufB, false);
            (void)xc;
        }
    }
#undef TAP

    size_t obase = ((size_t)(f1 * 32 + f2) << 10) + yy * 32 + x0;
    #pragma unroll
    for (int co = 0; co < CO; ++co) {
        float4 o;
        o.x = fmaxf(acc[co][0], 0.f);
        o.y = fmaxf(acc[co][1], 0.f);
        o.z = fmaxf(acc[co][2], 0.f);
        o.w = fmaxf(acc[co][3], 0.f);
        float* yp = y + ((size_t)co << 20) + obase;
        if (ADD) {
            float4 prev = *(const float4*)yp;
            o.x += prev.x; o.y += prev.y; o.z += prev.z; o.w += prev.w;
        }
        *(float4*)yp = o;
    }
}

extern "C" void kernel_launch(void* const* d_in, const int* in_sizes, int n_in,
                              void* d_out, int out_size, void* d_ws, size_t ws_size,
                              hipStream_t stream)
{
    (void)in_sizes; (void)n_in; (void)out_size; (void)ws_size;
    const float* fA = (const float*)d_in[0];
    const float* fB = (const float*)d_in[1];
    const float* w1 = (const float*)d_in[2];
    const float* b1 = (const float*)d_in[3];
    const float* w2 = (const float*)d_in[4];
    const float* b2 = (const float*)d_in[5];
    const float* w3 = (const float*)d_in[6];
    const float* b3 = (const float*)d_in[7];
    float* out = (float*)d_out;
    float* ws = (float*)d_ws;

    size_t o = 0;
    float* invA = ws + o; o += 4096;
    float* invB = ws + o; o += 4096;
    float* maxR = ws + o; o += 4096;
    float* maxC = ws + o; o += 4096;
    float* pw1  = ws + o; o += 2048;     // 2 x [1][27][32] = 2x864
    float* pw2  = ws + o; o += 18432;    // 2 x [10][27][32] = 2x8640
    float* pw3  = ws + o; o += 3072;     // 2 x [10][27][4]  = 2x1080
    float* corr = ws + o; o += 4194304;  // [4][1024][1024]
    float* t1   = ws + o; o += 10485760; // [10][32^4]
    float* t2   = ws + o; o += 10485760; // [10][32^4]

    invnorm_k<<<64, 256, 0, stream>>>(fA, invA);
    invnorm_k<<<64, 256, 0, stream>>>(fB, invB);
    corr_k<<<dim3(16, 16, 4), 256, 0, stream>>>(fA, fB, invA, invB, corr);

    // mutual matching #1 (in place on corr)
    rowmax_k<<<dim3(1024, 4), 256, 0, stream>>>(corr, maxR);
    hipMemsetAsync(maxC, 0, 4096 * sizeof(float), stream);
    colmax_k<<<dim3(4, 8, 4), 256, 0, stream>>>(corr, maxC);
    mmapply_k<<<4096, 256, 0, stream>>>(corr, maxR, maxC);

    // packed weights (A = normal, B = kernel-axis-permuted symmetric branch)
    packw_k<1, 10><<<4, 256, 0, stream>>>(w1, pw1, 0);
    packw_k<1, 10><<<4, 256, 0, stream>>>(w1, pw1 + 864, 1);
    packw_k<10, 10><<<34, 256, 0, stream>>>(w2, pw2, 0);
    packw_k<10, 10><<<34, 256, 0, stream>>>(w2, pw2 + 8640, 1);
    packw_k<10, 1><<<5, 256, 0, stream>>>(w3, pw3, 0);
    packw_k<10, 1><<<5, 256, 0, stream>>>(w3, pw3 + 1080, 1);

    for (int b = 0; b < 4; ++b) {
        const float* xb = corr + (size_t)b * 1048576;
        float* ob = out + (size_t)b * 1048576;
        conv4d_k<1, 10, false><<<1024, 256, 0, stream>>>(xb, pw1, b1, t1);
        conv4d_k<10, 10, false><<<1024, 256, 0, stream>>>(t1, pw2, b2, t2);
        conv4d_k<10, 1, false><<<1024, 256, 0, stream>>>(t2, pw3, b3, ob);
        conv4d_k<1, 10, false><<<1024, 256, 0, stream>>>(xb, pw1 + 864, b1, t1);
        conv4d_k<10, 10, false><<<1024, 256, 0, stream>>>(t1, pw2 + 8640, b2, t2);
        conv4d_k<10, 1, true ><<<1024, 256, 0, stream>>>(t2, pw3 + 1080, b3, ob);
    }

    // mutual matching #2 (in place on out)
    rowmax_k<<<dim3(1024, 4), 256, 0, stream>>>(out, maxR);
    hipMemsetAsync(maxC, 0, 4096 * sizeof(float), stream);
    colmax_k<<<dim3(4, 8, 4), 256, 0, stream>>>(out, maxC);
    mmapply_k<<<4096, 256, 0, stream>>>(out, maxR, maxC);
}

// Round 5
// 1828.697 us; speedup vs baseline: 3.4058x; 1.4331x over previous
//
#include <hip/hip_runtime.h>

#define EPSN 1e-6f
#define EPSM 1e-5f

typedef __fp16 h2v __attribute__((ext_vector_type(2)));

__device__ __forceinline__ unsigned pkh2(float a, float b) {
    union { h2v h; unsigned u; } v;
    v.h = __builtin_amdgcn_cvt_pkrtz(a, b);
    return v.u;
}

__device__ __forceinline__ float dot2f(unsigned a, unsigned b, float c) {
    union { unsigned u; h2v h; } ua, ub;
    ua.u = a; ub.u = b;
#if __has_builtin(__builtin_amdgcn_fdot2)
    return __builtin_amdgcn_fdot2(ua.h, ub.h, c, false);
#else
    return fmaf((float)ua.h.x, (float)ub.h.x,
                fmaf((float)ua.h.y, (float)ub.h.y, c));
#endif
}

// ---------------- inv L2-norm over channel dim (c=256) ----------------
__global__ __launch_bounds__(256) void invnorm_k(const float* __restrict__ f,
                                                 float* __restrict__ inv)
{
    int pbase = blockIdx.x * 64;
    int pp = threadIdx.x & 63;
    int cc = threadIdx.x >> 6;          // 0..3
    int pos = pbase + pp;               // b*1024 + ij
    int b = pos >> 10, ij = pos & 1023;
    const float* fp = f + (size_t)(b * 256) * 1024 + ij;
    float s = 0.f;
    #pragma unroll 8
    for (int k = 0; k < 64; ++k) {
        float v = fp[(size_t)(cc * 64 + k) * 1024];
        s += v * v;
    }
    __shared__ float red[4][64];
    red[cc][pp] = s;
    __syncthreads();
    if (cc == 0) {
        float t = red[0][pp] + red[1][pp] + red[2][pp] + red[3][pp];
        inv[pos] = rsqrtf(t + EPSN);
    }
}

// ---------------- correlation GEMM + relu + softsign ----------------
__global__ __launch_bounds__(256) void corr_k(const float* __restrict__ fa,
                                              const float* __restrict__ fb,
                                              const float* __restrict__ invA,
                                              const float* __restrict__ invB,
                                              float* __restrict__ corr)
{
    __shared__ float As[16][68];
    __shared__ float Bs[16][68];
    int b = blockIdx.z;
    int i0 = blockIdx.y * 64, j0 = blockIdx.x * 64;
    int tid = threadIdx.x;
    int tx = tid & 15, ty = tid >> 4;
    const float* fab = fa + (size_t)b * 256 * 1024;
    const float* fbb = fb + (size_t)b * 256 * 1024;
    const float* ia = invA + b * 1024 + i0;
    const float* ib = invB + b * 1024 + j0;
    float acc[4][4] = {};
    for (int kc = 0; kc < 256; kc += 16) {
        #pragma unroll
        for (int l = 0; l < 4; ++l) {
            int idx = tid + l * 256;
            int r = idx >> 6, cix = idx & 63;
            As[r][cix] = fab[(size_t)(kc + r) * 1024 + i0 + cix] * ia[cix];
            Bs[r][cix] = fbb[(size_t)(kc + r) * 1024 + j0 + cix] * ib[cix];
        }
        __syncthreads();
        #pragma unroll
        for (int k = 0; k < 16; ++k) {
            float4 av = *(const float4*)&As[k][ty * 4];
            float4 bv = *(const float4*)&Bs[k][tx * 4];
            float a[4] = {av.x, av.y, av.z, av.w};
            float bq[4] = {bv.x, bv.y, bv.z, bv.w};
            #pragma unroll
            for (int ii = 0; ii < 4; ++ii)
                #pragma unroll
                for (int jj = 0; jj < 4; ++jj)
                    acc[ii][jj] += a[ii] * bq[jj];
        }
        __syncthreads();
    }
    float* cb = corr + ((size_t)b << 20);
    #pragma unroll
    for (int ii = 0; ii < 4; ++ii) {
        float4 o; float v;
        v = fmaxf(acc[ii][0], 0.f); o.x = v * rsqrtf(v * v + EPSN);
        v = fmaxf(acc[ii][1], 0.f); o.y = v * rsqrtf(v * v + EPSN);
        v = fmaxf(acc[ii][2], 0.f); o.z = v * rsqrtf(v * v + EPSN);
        v = fmaxf(acc[ii][3], 0.f); o.w = v * rsqrtf(v * v + EPSN);
        *(float4*)&cb[(size_t)(i0 + ty * 4 + ii) * 1024 + j0 + tx * 4] = o;
    }
}

// ---------------- mutual matching ----------------
__global__ __launch_bounds__(256) void rowmax_k(const float* __restrict__ c,
                                                float* __restrict__ maxR)
{
    int b = blockIdx.y, i = blockIdx.x, tid = threadIdx.x;
    const float* row = c + ((size_t)b << 20) + ((size_t)i << 10);
    float m = fmaxf(fmaxf(row[tid], row[tid + 256]), fmaxf(row[tid + 512], row[tid + 768]));
    #pragma unroll
    for (int off = 32; off; off >>= 1) m = fmaxf(m, __shfl_down(m, off, 64));
    __shared__ float sred[4];
    if ((tid & 63) == 0) sred[tid >> 6] = m;
    __syncthreads();
    if (tid == 0)
        maxR[b * 1024 + i] = fmaxf(fmaxf(sred[0], sred[1]), fmaxf(sred[2], sred[3]));
}

__global__ __launch_bounds__(256) void colmax_k(const float* __restrict__ c,
                                                float* __restrict__ maxC)
{
    int j = blockIdx.x * 256 + threadIdx.x;
    int r0 = blockIdx.y * 128;
    int b = blockIdx.z;
    const float* cb = c + ((size_t)b << 20);
    float m = 0.f;
    for (int r = 0; r < 128; ++r) m = fmaxf(m, cb[(size_t)(r0 + r) * 1024 + j]);
    atomicMax((int*)&maxC[b * 1024 + j], __float_as_int(m));
}

__global__ __launch_bounds__(256) void mmapply_k(float* __restrict__ c,
                                                 const float* __restrict__ maxR,
                                                 const float* __restrict__ maxC)
{
    int e4 = blockIdx.x * 256 + threadIdx.x;
    int e = e4 * 4;
    int b = e >> 20, i = (e >> 10) & 1023, j0 = e & 1023;
    float4 v = ((float4*)c)[e4];
    float ra = 1.f / (maxR[b * 1024 + i] + EPSM);
    float4 mb = ((const float4*)maxC)[(b * 1024 + j0) >> 2];
    float4 o;
    o.x = v.x * v.x * v.x * ra / (mb.x + EPSM);
    o.y = v.y * v.y * v.y * ra / (mb.y + EPSM);
    o.z = v.z * v.z * v.z * ra / (mb.z + EPSM);
    o.w = v.w * v.w * v.w * ra / (mb.w + EPSM);
    ((float4*)c)[e4] = o;
}

// ---------------- f32 weight pack: [CO][CI][81] -> [CI][27(d123)][WS] ----------
// slot = d4*CO + co; perm: src tap (d1,d2,d3,d4) <- (d3,d4,d1,d2)
template <int CI, int CO>
__global__ void packw_k(const float* __restrict__ w, float* __restrict__ dst, int perm)
{
    constexpr int WS = (3 * CO + 3) & ~3;
    int idx = blockIdx.x * 256 + threadIdx.x;
    if (idx >= CI * 27 * WS) return;
    int ci = idx / (27 * WS);
    int rem = idx - ci * 27 * WS;
    int d123 = rem / WS;
    int slot = rem - d123 * WS;
    float v = 0.f;
    if (slot < 3 * CO) {
        int d4 = slot / CO, co = slot - d4 * CO;
        int t = d123 * 3 + d4;
        int d1 = t / 27, r2 = t % 27;
        int d2 = r2 / 9, r3 = r2 % 9;
        int d3 = r3 / 3, dd4 = r3 % 3;
        int st = perm ? (d3 * 27 + dd4 * 9 + d1 * 3 + d2) : t;
        v = w[(co * CI + ci) * 81 + st];
    }
    dst[idx] = v;
}

// ---------------- f16-pair weight pack: [CO][2*CIP][81] -> [CIP][27][WS] u32 ----
// elem = pkh2(w[co][2p][tap], w[co][2p+1][tap]); slot = d4*CO + co
template <int CIP, int CO>
__global__ void packw2_k(const float* __restrict__ w, unsigned* __restrict__ dst, int perm)
{
    constexpr int WS = (3 * CO + 3) & ~3;
    int idx = blockIdx.x * 256 + threadIdx.x;
    if (idx >= CIP * 27 * WS) return;
    int pp = idx / (27 * WS);
    int rem = idx - pp * 27 * WS;
    int d123 = rem / WS;
    int slot = rem - d123 * WS;
    unsigned v = 0u;
    if (slot < 3 * CO) {
        int d4 = slot / CO, co = slot - d4 * CO;
        int t = d123 * 3 + d4;
        int d1 = t / 27, r2 = t % 27;
        int d2 = r2 / 9, r3 = r2 % 9;
        int d3 = r3 / 3, dd4 = r3 % 3;
        int st = perm ? (d3 * 27 + dd4 * 9 + d1 * 3 + d2) : t;
        float f0 = w[(co * 2 * CIP + 2 * pp) * 81 + st];
        float f1 = w[(co * 2 * CIP + 2 * pp + 1) * 81 + st];
        v = pkh2(f0, f1);
    }
    dst[idx] = v;
}

// ---------------- f32 4D conv (layer 1, CI=1) -- round-3 proven version --------
template <int CI, int CO, bool ADD>
__global__ __launch_bounds__(256, 4) void conv4d_k(const float* __restrict__ x,
                                                   const float* __restrict__ wp,
                                                   const float* __restrict__ bias,
                                                   float* __restrict__ y)
{
    constexpr int WS = (3 * CO + 3) & ~3;
    constexpr int NW4 = WS / 4;
    constexpr int SLAB = 34 * 35;
    __shared__ float tile[3 * SLAB];

    int tid = threadIdx.x;
    int f1 = blockIdx.x >> 5, f2 = blockIdx.x & 31;
    int q = tid & 7, yy = tid >> 3;
    int x0 = q << 2;

    for (int e = tid; e < 3 * SLAB; e += 256) tile[e] = 0.f;

    float acc[CO][4];
    #pragma unroll
    for (int co = 0; co < CO; ++co) {
        float bv = bias[co];
        acc[co][0] = bv; acc[co][1] = bv; acc[co][2] = bv; acc[co][3] = bv;
    }

    float bufA[WS], bufB[WS];

#define TAP(U, WB, WN, PF) do {                                               \
        constexpr int u_ = (U);                                               \
        const float* rowb_ = &tile[(u_/3)*SLAB + (yy + u_%3)*35 + x0];        \
        float xs_[6];                                                         \
        _Pragma("unroll") for (int j = 0; j < 6; ++j) xs_[j] = rowb_[j];      \
        if (PF) {                                                             \
            _Pragma("unroll") for (int k = 0; k < NW4; ++k)                   \
                *(float4*)&WN[k*4] =                                          \
                    ((const float4*)(wphase + (u_+1)*WS))[k];                 \
        }                                                                     \
        _Pragma("unroll") for (int d4 = 0; d4 < 3; ++d4)                      \
        _Pragma("unroll") for (int co = 0; co < CO; ++co) {                   \
            float wf_ = WB[d4*CO + co];                                       \
            _Pragma("unroll") for (int p = 0; p < 4; ++p)                     \
                acc[co][p] = fmaf(xs_[p + d4], wf_, acc[co][p]);              \
        }                                                                     \
    } while (0)

    #pragma unroll 1
    for (int ci = 0; ci < CI; ++ci) {
        const float* wci = wp + ci * 27 * WS;
        #pragma unroll 1
        for (int d1 = 0; d1 < 3; ++d1) {
            int g1 = f1 + d1 - 1;
            bool g1ok = (unsigned)g1 < 32u;
            const float* wphase = wci + d1 * 9 * WS;
            __syncthreads();
            #pragma unroll
            for (int k = 0; k < NW4; ++k)
                *(float4*)&bufA[k*4] = ((const float4*)wphase)[k];
            #pragma unroll
            for (int it = 0; it < 3; ++it) {
                int e = tid + it * 256;
                int s2 = e >> 8, rr = (e >> 3) & 31, qq = e & 7;
                int g2 = f2 + s2 - 1;
                float4 v = {0.f, 0.f, 0.f, 0.f};
                if (g1ok & ((unsigned)g2 < 32u))
                    v = *(const float4*)&x[((size_t)ci << 20) +
                        ((size_t)((g1 << 5) + g2) << 10) + (rr << 5) + (qq << 2)];
                float* t = &tile[s2 * SLAB + (rr + 1) * 35 + 1 + (qq << 2)];
                t[0] = v.x; t[1] = v.y; t[2] = v.z; t[3] = v.w;
            }
            __syncthreads();

            TAP(0, bufA, bufB, true);
            TAP(1, bufB, bufA, true);
            TAP(2, bufA, bufB, true);
            TAP(3, bufB, bufA, true);
            TAP(4, bufA, bufB, true);
            TAP(5, bufB, bufA, true);
            TAP(6, bufA, bufB, true);
            TAP(7, bufB, bufA, true);
            TAP(8, bufA, bufB, false);
        }
    }
#undef TAP

    size_t obase = ((size_t)(f1 * 32 + f2) << 10) + yy * 32 + x0;
    #pragma unroll
    for (int co = 0; co < CO; ++co) {
        float4 o;
        o.x = fmaxf(acc[co][0], 0.f);
        o.y = fmaxf(acc[co][1], 0.f);
        o.z = fmaxf(acc[co][2], 0.f);
        o.w = fmaxf(acc[co][3], 0.f);
        float* yp = y + ((size_t)co << 20) + obase;
        if (ADD) {
            float4 prev = *(const float4*)yp;
            o.x += prev.x; o.y += prev.y; o.z += prev.z; o.w += prev.w;
        }
        *(float4*)yp = o;
    }
}

// ---------------- f16-pair 4D conv (layers 2,3): ci paired, v_dot2_f32_f16 ----
// x: [2*CIP][32^4] f32, wp: [CIP][27][WS] u32 (f16 pairs), y: [CO][32^4] f32
// LDS tile elems = packed f16 ci-pairs; same stride-35 layout as f32 version.
template <int CIP, int CO, bool ADD>
__global__ __launch_bounds__(256, 4) void conv4dp_k(const float* __restrict__ x,
                                                    const unsigned* __restrict__ wp,
                                                    const float* __restrict__ bias,
                                                    float* __restrict__ y)
{
    constexpr int WS = (3 * CO + 3) & ~3;     // u32 slots
    constexpr int NW4 = WS / 4;
    constexpr int SLAB = 34 * 35;
    __shared__ unsigned tile[3 * SLAB];       // 14280 B

    int tid = threadIdx.x;
    int f1 = blockIdx.x >> 5, f2 = blockIdx.x & 31;
    int q = tid & 7, yy = tid >> 3;
    int x0 = q << 2;

    for (int e = tid; e < 3 * SLAB; e += 256) tile[e] = 0u;

    float acc[CO][4];
    #pragma unroll
    for (int co = 0; co < CO; ++co) {
        float bv = bias[co];
        acc[co][0] = bv; acc[co][1] = bv; acc[co][2] = bv; acc[co][3] = bv;
    }

    unsigned bufA[WS], bufB[WS];

#define TAPP(U, WB, WN, PF) do {                                              \
        constexpr int u_ = (U);                                               \
        const unsigned* rowb_ = &tile[(u_/3)*SLAB + (yy + u_%3)*35 + x0];     \
        unsigned xs_[6];                                                      \
        _Pragma("unroll") for (int j = 0; j < 6; ++j) xs_[j] = rowb_[j];      \
        if (PF) {                                                             \
            _Pragma("unroll") for (int k = 0; k < NW4; ++k)                   \
                *(uint4*)&WN[k*4] =                                           \
                    ((const uint4*)(wphase + (u_+1)*WS))[k];                  \
        }                                                                     \
        _Pragma("unroll") for (int d4 = 0; d4 < 3; ++d4)                      \
        _Pragma("unroll") for (int co = 0; co < CO; ++co) {                   \
            unsigned wf_ = WB[d4*CO + co];                                    \
            _Pragma("unroll") for (int p = 0; p < 4; ++p)                     \
                acc[co][p] = dot2f(xs_[p + d4], wf_, acc[co][p]);             \
        }                                                                     \
    } while (0)

    #pragma unroll 1
    for (int pp = 0; pp < CIP; ++pp) {
        const float* xc0 = x + ((size_t)(2 * pp) << 20);
        const float* xc1 = x + ((size_t)(2 * pp + 1) << 20);
        const unsigned* wci = wp + pp * 27 * WS;
        #pragma unroll 1
        for (int d1 = 0; d1 < 3; ++d1) {
            int g1 = f1 + d1 - 1;
            bool g1ok = (unsigned)g1 < 32u;
            const unsigned* wphase = wci + d1 * 9 * WS;
            __syncthreads();
            #pragma unroll
            for (int k = 0; k < NW4; ++k)
                *(uint4*)&bufA[k*4] = ((const uint4*)wphase)[k];
            #pragma unroll
            for (int it = 0; it < 3; ++it) {
                int e = tid + it * 256;
                int s2 = e >> 8, rr = (e >> 3) & 31, qq = e & 7;
                int g2 = f2 + s2 - 1;
                float4 va = {0.f, 0.f, 0.f, 0.f};
                float4 vb = {0.f, 0.f, 0.f, 0.f};
                if (g1ok & ((unsigned)g2 < 32u)) {
                    size_t off = ((size_t)((g1 << 5) + g2) << 10) + (rr << 5) + (qq << 2);
                    va = *(const float4*)&xc0[off];
                    vb = *(const float4*)&xc1[off];
                }
                unsigned* t = &tile[s2 * SLAB + (rr + 1) * 35 + 1 + (qq << 2)];
                t[0] = pkh2(va.x, vb.x);
                t[1] = pkh2(va.y, vb.y);
                t[2] = pkh2(va.z, vb.z);
                t[3] = pkh2(va.w, vb.w);
            }
            __syncthreads();

            TAPP(0, bufA, bufB, true);
            TAPP(1, bufB, bufA, true);
            TAPP(2, bufA, bufB, true);
            TAPP(3, bufB, bufA, true);
            TAPP(4, bufA, bufB, true);
            TAPP(5, bufB, bufA, true);
            TAPP(6, bufA, bufB, true);
            TAPP(7, bufB, bufA, true);
            TAPP(8, bufA, bufB, false);
        }
    }
#undef TAPP

    size_t obase = ((size_t)(f1 * 32 + f2) << 10) + yy * 32 + x0;
    #pragma unroll
    for (int co = 0; co < CO; ++co) {
        float4 o;
        o.x = fmaxf(acc[co][0], 0.f);
        o.y = fmaxf(acc[co][1], 0.f);
        o.z = fmaxf(acc[co][2], 0.f);
        o.w = fmaxf(acc[co][3], 0.f);
        float* yp = y + ((size_t)co << 20) + obase;
        if (ADD) {
            float4 prev = *(const float4*)yp;
            o.x += prev.x; o.y += prev.y; o.z += prev.z; o.w += prev.w;
        }
        *(float4*)yp = o;
    }
}

extern "C" void kernel_launch(void* const* d_in, const int* in_sizes, int n_in,
                              void* d_out, int out_size, void* d_ws, size_t ws_size,
                              hipStream_t stream)
{
    (void)in_sizes; (void)n_in; (void)out_size; (void)ws_size;
    const float* fA = (const float*)d_in[0];
    const float* fB = (const float*)d_in[1];
    const float* w1 = (const float*)d_in[2];
    const float* b1 = (const float*)d_in[3];
    const float* w2 = (const float*)d_in[4];
    const float* b2 = (const float*)d_in[5];
    const float* w3 = (const float*)d_in[6];
    const float* b3 = (const float*)d_in[7];
    float* out = (float*)d_out;
    float* ws = (float*)d_ws;

    size_t o = 0;
    float* invA = ws + o; o += 4096;
    float* invB = ws + o; o += 4096;
    float* maxR = ws + o; o += 4096;
    float* maxC = ws + o; o += 4096;
    float* pw1  = ws + o; o += 2048;               // 2 x [1][27][32] f32
    unsigned* pw2 = (unsigned*)(ws + o); o += 8640; // 2 x [5][27][32] u32
    unsigned* pw3 = (unsigned*)(ws + o); o += 1080; // 2 x [5][27][4] u32
    float* corr = ws + o; o += 4194304;  // [4][1024][1024]
    float* t1   = ws + o; o += 10485760; // [10][32^4]
    float* t2   = ws + o; o += 10485760; // [10][32^4]

    invnorm_k<<<64, 256, 0, stream>>>(fA, invA);
    invnorm_k<<<64, 256, 0, stream>>>(fB, invB);
    corr_k<<<dim3(16, 16, 4), 256, 0, stream>>>(fA, fB, invA, invB, corr);

    // mutual matching #1 (in place on corr)
    rowmax_k<<<dim3(1024, 4), 256, 0, stream>>>(corr, maxR);
    (void)hipMemsetAsync(maxC, 0, 4096 * sizeof(float), stream);
    colmax_k<<<dim3(4, 8, 4), 256, 0, stream>>>(corr, maxC);
    mmapply_k<<<4096, 256, 0, stream>>>(corr, maxR, maxC);

    // packed weights (A = normal, B = kernel-axis-permuted symmetric branch)
    packw_k<1, 10><<<4, 256, 0, stream>>>(w1, pw1, 0);
    packw_k<1, 10><<<4, 256, 0, stream>>>(w1, pw1 + 864, 1);
    packw2_k<5, 10><<<17, 256, 0, stream>>>(w2, pw2, 0);
    packw2_k<5, 10><<<17, 256, 0, stream>>>(w2, pw2 + 4320, 1);
    packw2_k<5, 1><<<3, 256, 0, stream>>>(w3, pw3, 0);
    packw2_k<5, 1><<<3, 256, 0, stream>>>(w3, pw3 + 540, 1);

    for (int b = 0; b < 4; ++b) {
        const float* xb = corr + (size_t)b * 1048576;
        float* ob = out + (size_t)b * 1048576;
        conv4d_k<1, 10, false><<<1024, 256, 0, stream>>>(xb, pw1, b1, t1);
        conv4dp_k<5, 10, false><<<1024, 256, 0, stream>>>(t1, pw2, b2, t2);
        conv4dp_k<5, 1, false><<<1024, 256, 0, stream>>>(t2, pw3, b3, ob);
        conv4d_k<1, 10, false><<<1024, 256, 0, stream>>>(xb, pw1 + 864, b1, t1);
        conv4dp_k<5, 10, false><<<1024, 256, 0, stream>>>(t1, pw2 + 4320, b2, t2);
        conv4dp_k<5, 1, true ><<<1024, 256, 0, stream>>>(t2, pw3 + 540, b3, ob);
    }

    // mutual matching #2 (in place on out)
    rowmax_k<<<dim3(1024, 4), 256, 0, stream>>>(out, maxR);
    (void)hipMemsetAsync(maxC, 0, 4096 * sizeof(float), stream);
    colmax_k<<<dim3(4, 8, 4), 256, 0, stream>>>(out, maxC);
    mmapply_k<<<4096, 256, 0, stream>>>(out, maxR, maxC);
}

// Round 7
// 1659.046 us; speedup vs baseline: 3.7541x; 1.1023x over previous
//
#include <hip/hip_runtime.h>

#define EPSN 1e-6f
#define EPSM 1e-5f

typedef __fp16 h2v __attribute__((ext_vector_type(2)));
typedef __fp16 f16x4 __attribute__((ext_vector_type(4)));
typedef float f32x4 __attribute__((ext_vector_type(4)));

// legacy mai-insts spelling; present on gfx908..gfx950. No __has_builtin guard:
// amdgcn builtins are aux-target builtins in the host pass (usable, but
// __has_builtin reports false there).
#define MFMA16(a, b, c) __builtin_amdgcn_mfma_f32_16x16x16f16((a), (b), (c), 0, 0, 0)

__device__ __forceinline__ unsigned pkh2(float a, float b) {
    union { h2v h; unsigned u; } v;
    v.h = __builtin_amdgcn_cvt_pkrtz(a, b);
    return v.u;
}

__device__ __forceinline__ float dot2f(unsigned a, unsigned b, float c) {
    union { unsigned u; h2v h; } ua, ub;
    ua.u = a; ub.u = b;
#if __has_builtin(__builtin_amdgcn_fdot2)
    return __builtin_amdgcn_fdot2(ua.h, ub.h, c, false);
#else
    return fmaf((float)ua.h.x, (float)ub.h.x,
                fmaf((float)ua.h.y, (float)ub.h.y, c));
#endif
}

// ---------------- inv L2-norm over channel dim (c=256) ----------------
__global__ __launch_bounds__(256) void invnorm_k(const float* __restrict__ f,
                                                 float* __restrict__ inv)
{
    int pbase = blockIdx.x * 64;
    int pp = threadIdx.x & 63;
    int cc = threadIdx.x >> 6;
    int pos = pbase + pp;
    int b = pos >> 10, ij = pos & 1023;
    const float* fp = f + (size_t)(b * 256) * 1024 + ij;
    float s = 0.f;
    #pragma unroll 8
    for (int k = 0; k < 64; ++k) {
        float v = fp[(size_t)(cc * 64 + k) * 1024];
        s += v * v;
    }
    __shared__ float red[4][64];
    red[cc][pp] = s;
    __syncthreads();
    if (cc == 0) {
        float t = red[0][pp] + red[1][pp] + red[2][pp] + red[3][pp];
        inv[pos] = rsqrtf(t + EPSN);
    }
}

// ---------------- correlation GEMM + relu + softsign (fp32 - precision critical) ----
__global__ __launch_bounds__(256) void corr_k(const float* __restrict__ fa,
                                              const float* __restrict__ fb,
                                              const float* __restrict__ invA,
                                              const float* __restrict__ invB,
                                              float* __restrict__ corr)
{
    __shared__ float As[16][68];
    __shared__ float Bs[16][68];
    int b = blockIdx.z;
    int i0 = blockIdx.y * 64, j0 = blockIdx.x * 64;
    int tid = threadIdx.x;
    int tx = tid & 15, ty = tid >> 4;
    const float* fab = fa + (size_t)b * 256 * 1024;
    const float* fbb = fb + (size_t)b * 256 * 1024;
    const float* ia = invA + b * 1024 + i0;
    const float* ib = invB + b * 1024 + j0;
    float acc[4][4] = {};
    for (int kc = 0; kc < 256; kc += 16) {
        #pragma unroll
        for (int l = 0; l < 4; ++l) {
            int idx = tid + l * 256;
            int r = idx >> 6, cix = idx & 63;
            As[r][cix] = fab[(size_t)(kc + r) * 1024 + i0 + cix] * ia[cix];
            Bs[r][cix] = fbb[(size_t)(kc + r) * 1024 + j0 + cix] * ib[cix];
        }
        __syncthreads();
        #pragma unroll
        for (int k = 0; k < 16; ++k) {
            float4 av = *(const float4*)&As[k][ty * 4];
            float4 bv = *(const float4*)&Bs[k][tx * 4];
            float a[4] = {av.x, av.y, av.z, av.w};
            float bq[4] = {bv.x, bv.y, bv.z, bv.w};
            #pragma unroll
            for (int ii = 0; ii < 4; ++ii)
                #pragma unroll
                for (int jj = 0; jj < 4; ++jj)
                    acc[ii][jj] += a[ii] * bq[jj];
        }
        __syncthreads();
    }
    float* cb = corr + ((size_t)b << 20);
    #pragma unroll
    for (int ii = 0; ii < 4; ++ii) {
        float4 o; float v;
        v = fmaxf(acc[ii][0], 0.f); o.x = v * rsqrtf(v * v + EPSN);
        v = fmaxf(acc[ii][1], 0.f); o.y = v * rsqrtf(v * v + EPSN);
        v = fmaxf(acc[ii][2], 0.f); o.z = v * rsqrtf(v * v + EPSN);
        v = fmaxf(acc[ii][3], 0.f); o.w = v * rsqrtf(v * v + EPSN);
        *(float4*)&cb[(size_t)(i0 + ty * 4 + ii) * 1024 + j0 + tx * 4] = o;
    }
}

// ---------------- mutual matching ----------------
__global__ __launch_bounds__(256) void rowmax_k(const float* __restrict__ c,
                                                float* __restrict__ maxR)
{
    int b = blockIdx.y, i = blockIdx.x, tid = threadIdx.x;
    const float* row = c + ((size_t)b << 20) + ((size_t)i << 10);
    float m = fmaxf(fmaxf(row[tid], row[tid + 256]), fmaxf(row[tid + 512], row[tid + 768]));
    #pragma unroll
    for (int off = 32; off; off >>= 1) m = fmaxf(m, __shfl_down(m, off, 64));
    __shared__ float sred[4];
    if ((tid & 63) == 0) sred[tid >> 6] = m;
    __syncthreads();
    if (tid == 0)
        maxR[b * 1024 + i] = fmaxf(fmaxf(sred[0], sred[1]), fmaxf(sred[2], sred[3]));
}

__global__ __launch_bounds__(256) void colmax_k(const float* __restrict__ c,
                                                float* __restrict__ maxC)
{
    int j = blockIdx.x * 256 + threadIdx.x;
    int r0 = blockIdx.y * 128;
    int b = blockIdx.z;
    const float* cb = c + ((size_t)b << 20);
    float m = 0.f;
    for (int r = 0; r < 128; ++r) m = fmaxf(m, cb[(size_t)(r0 + r) * 1024 + j]);
    atomicMax((int*)&maxC[b * 1024 + j], __float_as_int(m));
}

__global__ __launch_bounds__(256) void mmapply_k(float* __restrict__ c,
                                                 const float* __restrict__ maxR,
                                                 const float* __restrict__ maxC)
{
    int e4 = blockIdx.x * 256 + threadIdx.x;
    int e = e4 * 4;
    int b = e >> 20, i = (e >> 10) & 1023, j0 = e & 1023;
    float4 v = ((float4*)c)[e4];
    float ra = 1.f / (maxR[b * 1024 + i] + EPSM);
    float4 mb = ((const float4*)maxC)[(b * 1024 + j0) >> 2];
    float4 o;
    o.x = v.x * v.x * v.x * ra / (mb.x + EPSM);
    o.y = v.y * v.y * v.y * ra / (mb.y + EPSM);
    o.z = v.z * v.z * v.z * ra / (mb.z + EPSM);
    o.w = v.w * v.w * v.w * ra / (mb.w + EPSM);
    ((float4*)c)[e4] = o;
}

// ---------------- f32 weight pack (layer 1): [CO][CI][81] -> [CI][27][WS] ------
template <int CI, int CO>
__global__ void packw_k(const float* __restrict__ w, float* __restrict__ dst, int perm)
{
    constexpr int WS = (3 * CO + 3) & ~3;
    int idx = blockIdx.x * 256 + threadIdx.x;
    if (idx >= CI * 27 * WS) return;
    int ci = idx / (27 * WS);
    int rem = idx - ci * 27 * WS;
    int d123 = rem / WS;
    int slot = rem - d123 * WS;
    float v = 0.f;
    if (slot < 3 * CO) {
        int d4 = slot / CO, co = slot - d4 * CO;
        int t = d123 * 3 + d4;
        int d1 = t / 27, r2 = t % 27;
        int d2 = r2 / 9, r3 = r2 % 9;
        int d3 = r3 / 3, dd4 = r3 % 3;
        int st = perm ? (d3 * 27 + dd4 * 9 + d1 * 3 + d2) : t;
        v = w[(co * CI + ci) * 81 + st];
    }
    dst[idx] = v;
}

// ---------------- mfma weight pack (layer 2): [10][10][81] -> [81][co16][k16] f16
__global__ void packwm_k(const float* __restrict__ w, unsigned short* __restrict__ dst,
                         int perm)
{
    int idx = blockIdx.x * 256 + threadIdx.x;   // 81*256 = 20736
    if (idx >= 20736) return;
    int tap = idx >> 8;
    int co  = (idx >> 4) & 15;
    int k   = idx & 15;
    float v = 0.f;
    if (co < 10 && k < 10) {
        int d1 = tap / 27, r2 = tap % 27;
        int d2 = r2 / 9, r3 = r2 % 9;
        int d3 = r3 / 3, d4 = r3 % 3;
        int st = perm ? (d3 * 27 + d4 * 9 + d1 * 3 + d2) : tap;
        v = w[(co * 10 + k) * 81 + st];
    }
    union { __fp16 h; unsigned short u; } cv;
    cv.h = (__fp16)v;
    dst[idx] = cv.u;
}

// ---------------- f16-pair weight pack (layer 3): [CO][2*CIP][81] -> [CIP][27][WS]
template <int CIP, int CO>
__global__ void packw2_k(const float* __restrict__ w, unsigned* __restrict__ dst, int perm)
{
    constexpr int WS = (3 * CO + 3) & ~3;
    int idx = blockIdx.x * 256 + threadIdx.x;
    if (idx >= CIP * 27 * WS) return;
    int pp = idx / (27 * WS);
    int rem = idx - pp * 27 * WS;
    int d123 = rem / WS;
    int slot = rem - d123 * WS;
    unsigned v = 0u;
    if (slot < 3 * CO) {
        int d4 = slot / CO, co = slot - d4 * CO;
        int t = d123 * 3 + d4;
        int d1 = t / 27, r2 = t % 27;
        int d2 = r2 / 9, r3 = r2 % 9;
        int d3 = r3 / 3, dd4 = r3 % 3;
        int st = perm ? (d3 * 27 + dd4 * 9 + d1 * 3 + d2) : t;
        float f0 = w[(co * 2 * CIP + 2 * pp) * 81 + st];
        float f1 = w[(co * 2 * CIP + 2 * pp + 1) * 81 + st];
        v = pkh2(f0, f1);
    }
    dst[idx] = v;
}

// ---------------- f32 4D conv (layer 1, CI=1), optional packed-f16-pair output --
template <int CI, int CO, bool ADD, bool PACK>
__global__ __launch_bounds__(256, 4) void conv4d_k(const float* __restrict__ x,
                                                   const float* __restrict__ wp,
                                                   const float* __restrict__ bias,
                                                   float* __restrict__ y)
{
    constexpr int WS = (3 * CO + 3) & ~3;
    constexpr int NW4 = WS / 4;
    constexpr int SLAB = 34 * 35;
    __shared__ float tile[3 * SLAB];

    int tid = threadIdx.x;
    int f1 = blockIdx.x >> 5, f2 = blockIdx.x & 31;
    int q = tid & 7, yy = tid >> 3;
    int x0 = q << 2;

    for (int e = tid; e < 3 * SLAB; e += 256) tile[e] = 0.f;

    float acc[CO][4];
    #pragma unroll
    for (int co = 0; co < CO; ++co) {
        float bv = bias[co];
        acc[co][0] = bv; acc[co][1] = bv; acc[co][2] = bv; acc[co][3] = bv;
    }

    float bufA[WS], bufB[WS];

#define TAP(U, WB, WN, PF) do {                                               \
        constexpr int u_ = (U);                                               \
        const float* rowb_ = &tile[(u_/3)*SLAB + (yy + u_%3)*35 + x0];        \
        float xs_[6];                                                         \
        _Pragma("unroll") for (int j = 0; j < 6; ++j) xs_[j] = rowb_[j];      \
        if (PF) {                                                             \
            _Pragma("unroll") for (int k = 0; k < NW4; ++k)                   \
                *(float4*)&WN[k*4] =                                          \
                    ((const float4*)(wphase + (u_+1)*WS))[k];                 \
        }                                                                     \
        _Pragma("unroll") for (int d4 = 0; d4 < 3; ++d4)                      \
        _Pragma("unroll") for (int co = 0; co < CO; ++co) {                   \
            float wf_ = WB[d4*CO + co];                                       \
            _Pragma("unroll") for (int p = 0; p < 4; ++p)                     \
                acc[co][p] = fmaf(xs_[p + d4], wf_, acc[co][p]);              \
        }                                                                     \
    } while (0)

    #pragma unroll 1
    for (int ci = 0; ci < CI; ++ci) {
        const float* wci = wp + ci * 27 * WS;
        #pragma unroll 1
        for (int d1 = 0; d1 < 3; ++d1) {
            int g1 = f1 + d1 - 1;
            bool g1ok = (unsigned)g1 < 32u;
            const float* wphase = wci + d1 * 9 * WS;
            __syncthreads();
            #pragma unroll
            for (int k = 0; k < NW4; ++k)
                *(float4*)&bufA[k*4] = ((const float4*)wphase)[k];
            #pragma unroll
            for (int it = 0; it < 3; ++it) {
                int e = tid + it * 256;
                int s2 = e >> 8, rr = (e >> 3) & 31, qq = e & 7;
                int g2 = f2 + s2 - 1;
                float4 v = {0.f, 0.f, 0.f, 0.f};
                if (g1ok & ((unsigned)g2 < 32u))
                    v = *(const float4*)&x[((size_t)ci << 20) +
                        ((size_t)((g1 << 5) + g2) << 10) + (rr << 5) + (qq << 2)];
                float* t = &tile[s2 * SLAB + (rr + 1) * 35 + 1 + (qq << 2)];
                t[0] = v.x; t[1] = v.y; t[2] = v.z; t[3] = v.w;
            }
            __syncthreads();

            TAP(0, bufA, bufB, true);
            TAP(1, bufB, bufA, true);
            TAP(2, bufA, bufB, true);
            TAP(3, bufB, bufA, true);
            TAP(4, bufA, bufB, true);
            TAP(5, bufB, bufA, true);
            TAP(6, bufA, bufB, true);
            TAP(7, bufB, bufA, true);
            TAP(8, bufA, bufB, false);
        }
    }
#undef TAP

    size_t obase = ((size_t)(f1 * 32 + f2) << 10) + yy * 32 + x0;
    if (PACK) {
        // packed f16 ci-pair output: [CO/2][1M] u32
        unsigned* ypu = (unsigned*)y;
        #pragma unroll
        for (int c = 0; c < CO / 2; ++c) {
            uint4 o;
            o.x = pkh2(fmaxf(acc[2*c][0], 0.f), fmaxf(acc[2*c+1][0], 0.f));
            o.y = pkh2(fmaxf(acc[2*c][1], 0.f), fmaxf(acc[2*c+1][1], 0.f));
            o.z = pkh2(fmaxf(acc[2*c][2], 0.f), fmaxf(acc[2*c+1][2], 0.f));
            o.w = pkh2(fmaxf(acc[2*c][3], 0.f), fmaxf(acc[2*c+1][3], 0.f));
            *(uint4*)&ypu[(size_t)c * 1048576 + obase] = o;
        }
    } else {
        #pragma unroll
        for (int co = 0; co < CO; ++co) {
            float4 o;
            o.x = fmaxf(acc[co][0], 0.f);
            o.y = fmaxf(acc[co][1], 0.f);
            o.z = fmaxf(acc[co][2], 0.f);
            o.w = fmaxf(acc[co][3], 0.f);
            float* yp = y + ((size_t)co << 20) + obase;
            if (ADD) {
                float4 prev = *(const float4*)yp;
                o.x += prev.x; o.y += prev.y; o.z += prev.z; o.w += prev.w;
            }
            *(float4*)yp = o;
        }
    }
}

// ---------------- MFMA 4D conv (layer 2: CI=10, CO=10) ------------------------
// xp: [5][1M] u32 (f16 ci-pairs), wm: [81][co16][k16] f16, yp: [5][1M] u32 pairs
// block = (f1, f2, f3-quarter). LDS x-tile ci-interleaved:
//   tile[s2(d2) 0..2][row 0..9][col 0..33][ci 0..17 f16] stride-18 (bank-safe),
//   as u32 pairs: [..][..][..][9 u32]. Pads (ci>=10, col 0/33) zeroed once.
// Per tap (81): D[co][s] += A(w co x k) * B(x k x s) via 16x16x16 f16 mfma.
__global__ __launch_bounds__(256, 4) void conv4dm_k(const unsigned* __restrict__ xp,
                                                    const unsigned short* __restrict__ wm,
                                                    const float* __restrict__ bias,
                                                    unsigned* __restrict__ yp)
{
    __shared__ unsigned tile[3 * 10 * 34 * 9];   // 9180 u32 = 36720 B

    int tid = threadIdx.x;
    int bx = blockIdx.x;
    int q  = bx & 3;
    int f2 = (bx >> 2) & 31;
    int f1 = bx >> 7;
    int l  = tid & 63;
    int wv = tid >> 6;        // wave 0..3
    int sl = l & 15;          // A: co-row; B/D: spatial col
    int g  = l >> 4;          // k-group / D row-group

    for (int e = tid; e < 9180; e += 256) tile[e] = 0u;

    f32x4 bv;
    #pragma unroll
    for (int e = 0; e < 4; ++e) {
        int co = 4 * g + e;
        bv[e] = (co < 10) ? bias[co] : 0.f;
    }
    f32x4 acc0 = bv, acc1 = bv, acc2 = bv, acc3 = bv;

    int qbase = q * 8;

    #pragma unroll 1
    for (int d1 = 0; d1 < 3; ++d1) {
        int g1 = f1 + d1 - 1;
        bool g1ok = (unsigned)g1 < 32u;
        __syncthreads();   // previous-phase tile consumers done

        // prefetch this phase's 27 A-fragments (w[tap][co=sl][k=4g..4g+3])
        uint2 aw[27];
        #pragma unroll
        for (int t27 = 0; t27 < 27; ++t27) {
            int tap = d1 * 27 + t27;
            aw[t27] = *(const uint2*)&wm[(tap << 8) + (sl << 4) + (g << 2)];
        }

        // stage: 3 slabs x 10 rows x 32 interior cols = 960 positions, 5 u32 each
        #pragma unroll
        for (int it = 0; it < 4; ++it) {
            int e = tid + it * 256;
            if (e < 960) {
                int c  = (e & 31) + 1;
                int rg = e >> 5;
                int r  = rg % 10;
                int s2 = rg / 10;
                int g2 = f2 + s2 - 1;
                int g3 = qbase + r - 1;
                unsigned v0 = 0, v1 = 0, v2 = 0, v3 = 0, v4 = 0;
                if (g1ok & ((unsigned)g2 < 32u) & ((unsigned)g3 < 32u)) {
                    size_t off = ((size_t)((g1 << 5) + g2) << 10) + (g3 << 5) + (c - 1);
                    v0 = xp[off];
                    v1 = xp[off + 1048576];
                    v2 = xp[off + 2097152];
                    v3 = xp[off + 3145728];
                    v4 = xp[off + 4194304];
                }
                unsigned* t = &tile[((s2 * 10 + r) * 34 + c) * 9];
                t[0] = v0; t[1] = v1; t[2] = v2; t[3] = v3; t[4] = v4;
            }
        }
        __syncthreads();

        // compute: 27 taps x 4 tiles (2 rows x 2 col-halves per wave)
        int tb0 = ((wv * 2 + 0) * 34 + sl) * 9 + (g << 1);   // row rt=2wv,  ch=0
        #pragma unroll
        for (int d2 = 0; d2 < 3; ++d2)
        #pragma unroll
        for (int d3 = 0; d3 < 3; ++d3)
        #pragma unroll
        for (int d4 = 0; d4 < 3; ++d4) {
            int t27 = d2 * 9 + d3 * 3 + d4;
            union { uint2 u; f16x4 h; } A; A.u = aw[t27];
            int tapoff = ((d2 * 10 + d3) * 34 + d4) * 9;     // compile-time per tap
            const unsigned* bp = &tile[tb0 + tapoff];
            union { uint2 u; f16x4 h; } B;
            B.u.x = bp[0];           B.u.y = bp[1];
            acc0 = MFMA16(A.h, B.h, acc0);
            B.u.x = bp[16 * 9];      B.u.y = bp[16 * 9 + 1];       // ch=1
            acc1 = MFMA16(A.h, B.h, acc1);
            B.u.x = bp[34 * 9];      B.u.y = bp[34 * 9 + 1];       // rt=2wv+1
            acc2 = MFMA16(A.h, B.h, acc2);
            B.u.x = bp[50 * 9];      B.u.y = bp[50 * 9 + 1];       // rt+1, ch=1
            acc3 = MFMA16(A.h, B.h, acc3);
        }
    }

    // epilogue: relu, pack co-pairs, store. D: col(spatial)=sl, row(co)=4g+reg.
    size_t pbase = ((size_t)((f1 << 5) + f2) << 10);
#define STORE_TILE(ACC, RT, CH) do {                                          \
        size_t sidx = pbase + ((size_t)(qbase + (RT)) << 5) + (CH) * 16 + sl; \
        float r0 = fmaxf((ACC)[0], 0.f), r1 = fmaxf((ACC)[1], 0.f);           \
        float r2 = fmaxf((ACC)[2], 0.f), r3 = fmaxf((ACC)[3], 0.f);           \
        if (g < 2) {                                                          \
            yp[(size_t)(2 * g)     * 1048576 + sidx] = pkh2(r0, r1);          \
            yp[(size_t)(2 * g + 1) * 1048576 + sidx] = pkh2(r2, r3);          \
        } else if (g == 2) {                                                  \
            yp[(size_t)4 * 1048576 + sidx] = pkh2(r0, r1);                    \
        }                                                                     \
    } while (0)
    STORE_TILE(acc0, wv * 2 + 0, 0);
    STORE_TILE(acc1, wv * 2 + 0, 1);
    STORE_TILE(acc2, wv * 2 + 1, 0);
    STORE_TILE(acc3, wv * 2 + 1, 1);
#undef STORE_TILE
}

// ---------------- f16-pair 4D conv (layer 3): packed-pair input, dot2 ---------
// xp: [CIP][1M] u32 (f16 ci-pairs), wp: [CIP][27][WS] u32 pairs, y: [CO][1M] f32
template <int CIP, int CO, bool ADD>
__global__ __launch_bounds__(256, 4) void conv4dp_k(const unsigned* __restrict__ xp,
                                                    const unsigned* __restrict__ wp,
                                                    const float* __restrict__ bias,
                                                    float* __restrict__ y)
{
    constexpr int WS = (3 * CO + 3) & ~3;
    constexpr int NW4 = WS / 4;
    constexpr int SLAB = 34 * 35;
    __shared__ unsigned tile[3 * SLAB];

    int tid = threadIdx.x;
    int f1 = blockIdx.x >> 5, f2 = blockIdx.x & 31;
    int q = tid & 7, yy = tid >> 3;
    int x0 = q << 2;

    for (int e = tid; e < 3 * SLAB; e += 256) tile[e] = 0u;

    float acc[CO][4];
    #pragma unroll
    for (int co = 0; co < CO; ++co) {
        float bvv = bias[co];
        acc[co][0] = bvv; acc[co][1] = bvv; acc[co][2] = bvv; acc[co][3] = bvv;
    }

    unsigned bufA[WS], bufB[WS];

#define TAPP(U, WB, WN, PF) do {                                              \
        constexpr int u_ = (U);                                               \
        const unsigned* rowb_ = &tile[(u_/3)*SLAB + (yy + u_%3)*35 + x0];     \
        unsigned xs_[6];                                                      \
        _Pragma("unroll") for (int j = 0; j < 6; ++j) xs_[j] = rowb_[j];      \
        if (PF) {                                                             \
            _Pragma("unroll") for (int k = 0; k < NW4; ++k)                   \
                *(uint4*)&WN[k*4] =                                           \
                    ((const uint4*)(wphase + (u_+1)*WS))[k];                  \
        }                                                                     \
        _Pragma("unroll") for (int d4 = 0; d4 < 3; ++d4)                      \
        _Pragma("unroll") for (int co = 0; co < CO; ++co) {                   \
            unsigned wf_ = WB[d4*CO + co];                                    \
            _Pragma("unroll") for (int p = 0; p < 4; ++p)                     \
                acc[co][p] = dot2f(xs_[p + d4], wf_, acc[co][p]);             \
        }                                                                     \
    } while (0)

    #pragma unroll 1
    for (int pp = 0; pp < CIP; ++pp) {
        const unsigned* wci = wp + pp * 27 * WS;
        #pragma unroll 1
        for (int d1 = 0; d1 < 3; ++d1) {
            int g1 = f1 + d1 - 1;
            bool g1ok = (unsigned)g1 < 32u;
            const unsigned* wphase = wci + d1 * 9 * WS;
            __syncthreads();
            #pragma unroll
            for (int k = 0; k < NW4; ++k)
                *(uint4*)&bufA[k*4] = ((const uint4*)wphase)[k];
            #pragma unroll
            for (int it = 0; it < 3; ++it) {
                int e = tid + it * 256;
                int s2 = e >> 8, rr = (e >> 3) & 31, qq = e & 7;
                int g2 = f2 + s2 - 1;
                uint4 v = {0u, 0u, 0u, 0u};
                if (g1ok & ((unsigned)g2 < 32u))
                    v = *(const uint4*)&xp[((size_t)pp << 20) +
                        ((size_t)((g1 << 5) + g2) << 10) + (rr << 5) + (qq << 2)];
                unsigned* t = &tile[s2 * SLAB + (rr + 1) * 35 + 1 + (qq << 2)];
                t[0] = v.x; t[1] = v.y; t[2] = v.z; t[3] = v.w;
            }
            __syncthreads();

            TAPP(0, bufA, bufB, true);
            TAPP(1, bufB, bufA, true);
            TAPP(2, bufA, bufB, true);
            TAPP(3, bufB, bufA, true);
            TAPP(4, bufA, bufB, true);
            TAPP(5, bufB, bufA, true);
            TAPP(6, bufA, bufB, true);
            TAPP(7, bufB, bufA, true);
            TAPP(8, bufA, bufB, false);
        }
    }
#undef TAPP

    size_t obase = ((size_t)(f1 * 32 + f2) << 10) + yy * 32 + x0;
    #pragma unroll
    for (int co = 0; co < CO; ++co) {
        float4 o;
        o.x = fmaxf(acc[co][0], 0.f);
        o.y = fmaxf(acc[co][1], 0.f);
        o.z = fmaxf(acc[co][2], 0.f);
        o.w = fmaxf(acc[co][3], 0.f);
        float* ypt = y + ((size_t)co << 20) + obase;
        if (ADD) {
            float4 prev = *(const float4*)ypt;
            o.x += prev.x; o.y += prev.y; o.z += prev.z; o.w += prev.w;
        }
        *(float4*)ypt = o;
    }
}

extern "C" void kernel_launch(void* const* d_in, const int* in_sizes, int n_in,
                              void* d_out, int out_size, void* d_ws, size_t ws_size,
                              hipStream_t stream)
{
    (void)in_sizes; (void)n_in; (void)out_size; (void)ws_size;
    const float* fA = (const float*)d_in[0];
    const float* fB = (const float*)d_in[1];
    const float* w1 = (const float*)d_in[2];
    const float* b1 = (const float*)d_in[3];
    const float* w2 = (const float*)d_in[4];
    const float* b2 = (const float*)d_in[5];
    const float* w3 = (const float*)d_in[6];
    const float* b3 = (const float*)d_in[7];
    float* out = (float*)d_out;
    float* ws = (float*)d_ws;

    size_t o = 0;
    float* invA = ws + o; o += 4096;
    float* invB = ws + o; o += 4096;
    float* maxR = ws + o; o += 4096;
    float* maxC = ws + o; o += 4096;
    float* pw1  = ws + o; o += 2048;                       // 2 x [1][27][32] f32
    unsigned short* wm2 = (unsigned short*)(ws + o); o += 20736;  // 2 x 20736 ushort
    unsigned* pw3 = (unsigned*)(ws + o); o += 1080;        // 2 x [5][27][4] u32
    float* corr = ws + o; o += 4194304;                    // [4][1024][1024]
    unsigned* t1p = (unsigned*)(ws + o); o += 5242880;     // [5][1M] u32 pairs
    unsigned* t2p = (unsigned*)(ws + o); o += 5242880;     // [5][1M] u32 pairs

    invnorm_k<<<64, 256, 0, stream>>>(fA, invA);
    invnorm_k<<<64, 256, 0, stream>>>(fB, invB);
    corr_k<<<dim3(16, 16, 4), 256, 0, stream>>>(fA, fB, invA, invB, corr);

    // mutual matching #1 (in place on corr)
    rowmax_k<<<dim3(1024, 4), 256, 0, stream>>>(corr, maxR);
    (void)hipMemsetAsync(maxC, 0, 4096 * sizeof(float), stream);
    colmax_k<<<dim3(4, 8, 4), 256, 0, stream>>>(corr, maxC);
    mmapply_k<<<4096, 256, 0, stream>>>(corr, maxR, maxC);

    // packed weights (A = normal, B = kernel-axis-permuted symmetric branch)
    packw_k<1, 10><<<4, 256, 0, stream>>>(w1, pw1, 0);
    packw_k<1, 10><<<4, 256, 0, stream>>>(w1, pw1 + 864, 1);
    packwm_k<<<81, 256, 0, stream>>>(w2, wm2, 0);
    packwm_k<<<81, 256, 0, stream>>>(w2, wm2 + 20736, 1);
    packw2_k<5, 1><<<3, 256, 0, stream>>>(w3, pw3, 0);
    packw2_k<5, 1><<<3, 256, 0, stream>>>(w3, pw3 + 540, 1);

    for (int b = 0; b < 4; ++b) {
        const float* xb = corr + (size_t)b * 1048576;
        float* ob = out + (size_t)b * 1048576;
        conv4d_k<1, 10, false, true><<<1024, 256, 0, stream>>>(xb, pw1, b1, (float*)t1p);
        conv4dm_k<<<4096, 256, 0, stream>>>(t1p, wm2, b2, t2p);
        conv4dp_k<5, 1, false><<<1024, 256, 0, stream>>>(t2p, pw3, b3, ob);
        conv4d_k<1, 10, false, true><<<1024, 256, 0, stream>>>(xb, pw1 + 864, b1, (float*)t1p);
        conv4dm_k<<<4096, 256, 0, stream>>>(t1p, wm2 + 20736, b2, t2p);
        conv4dp_k<5, 1, true ><<<1024, 256, 0, stream>>>(t2p, pw3 + 540, b3, ob);
    }

    // mutual matching #2 (in place on out)
    rowmax_k<<<dim3(1024, 4), 256, 0, stream>>>(out, maxR);
    (void)hipMemsetAsync(maxC, 0, 4096 * sizeof(float), stream);
    colmax_k<<<dim3(4, 8, 4), 256, 0, stream>>>(out, maxC);
    mmapply_k<<<4096, 256, 0, stream>>>(out, maxR, maxC);
}

// Round 8
// 1565.031 us; speedup vs baseline: 3.9796x; 1.0601x over previous
//
#include <hip/hip_runtime.h>

#define EPSN 1e-6f
#define EPSM 1e-5f

typedef __fp16 h2v __attribute__((ext_vector_type(2)));
typedef __fp16 f16x4 __attribute__((ext_vector_type(4)));
typedef float f32x4 __attribute__((ext_vector_type(4)));

// legacy mai-insts spelling; present on gfx908..gfx950. No __has_builtin guard:
// amdgcn builtins are aux-target builtins in the host pass (usable, but
// __has_builtin reports false there).
#define MFMA16(a, b, c) __builtin_amdgcn_mfma_f32_16x16x16f16((a), (b), (c), 0, 0, 0)

__device__ __forceinline__ unsigned pkh2(float a, float b) {
    union { h2v h; unsigned u; } v;
    v.h = __builtin_amdgcn_cvt_pkrtz(a, b);
    return v.u;
}

__device__ __forceinline__ float dot2f(unsigned a, unsigned b, float c) {
    union { unsigned u; h2v h; } ua, ub;
    ua.u = a; ub.u = b;
#if __has_builtin(__builtin_amdgcn_fdot2)
    return __builtin_amdgcn_fdot2(ua.h, ub.h, c, false);
#else
    return fmaf((float)ua.h.x, (float)ub.h.x,
                fmaf((float)ua.h.y, (float)ub.h.y, c));
#endif
}

// ---------------- inv L2-norm over channel dim (c=256) ----------------
__global__ __launch_bounds__(256) void invnorm_k(const float* __restrict__ f,
                                                 float* __restrict__ inv)
{
    int pbase = blockIdx.x * 64;
    int pp = threadIdx.x & 63;
    int cc = threadIdx.x >> 6;
    int pos = pbase + pp;
    int b = pos >> 10, ij = pos & 1023;
    const float* fp = f + (size_t)(b * 256) * 1024 + ij;
    float s = 0.f;
    #pragma unroll 8
    for (int k = 0; k < 64; ++k) {
        float v = fp[(size_t)(cc * 64 + k) * 1024];
        s += v * v;
    }
    __shared__ float red[4][64];
    red[cc][pp] = s;
    __syncthreads();
    if (cc == 0) {
        float t = red[0][pp] + red[1][pp] + red[2][pp] + red[3][pp];
        inv[pos] = rsqrtf(t + EPSN);
    }
}

// ---------------- correlation GEMM + relu + softsign (fp32 - precision critical) ----
__global__ __launch_bounds__(256) void corr_k(const float* __restrict__ fa,
                                              const float* __restrict__ fb,
                                              const float* __restrict__ invA,
                                              const float* __restrict__ invB,
                                              float* __restrict__ corr)
{
    __shared__ float As[16][68];
    __shared__ float Bs[16][68];
    int b = blockIdx.z;
    int i0 = blockIdx.y * 64, j0 = blockIdx.x * 64;
    int tid = threadIdx.x;
    int tx = tid & 15, ty = tid >> 4;
    const float* fab = fa + (size_t)b * 256 * 1024;
    const float* fbb = fb + (size_t)b * 256 * 1024;
    const float* ia = invA + b * 1024 + i0;
    const float* ib = invB + b * 1024 + j0;
    float acc[4][4] = {};
    for (int kc = 0; kc < 256; kc += 16) {
        #pragma unroll
        for (int l = 0; l < 4; ++l) {
            int idx = tid + l * 256;
            int r = idx >> 6, cix = idx & 63;
            As[r][cix] = fab[(size_t)(kc + r) * 1024 + i0 + cix] * ia[cix];
            Bs[r][cix] = fbb[(size_t)(kc + r) * 1024 + j0 + cix] * ib[cix];
        }
        __syncthreads();
        #pragma unroll
        for (int k = 0; k < 16; ++k) {
            float4 av = *(const float4*)&As[k][ty * 4];
            float4 bv = *(const float4*)&Bs[k][tx * 4];
            float a[4] = {av.x, av.y, av.z, av.w};
            float bq[4] = {bv.x, bv.y, bv.z, bv.w};
            #pragma unroll
            for (int ii = 0; ii < 4; ++ii)
                #pragma unroll
                for (int jj = 0; jj < 4; ++jj)
                    acc[ii][jj] += a[ii] * bq[jj];
        }
        __syncthreads();
    }
    float* cb = corr + ((size_t)b << 20);
    #pragma unroll
    for (int ii = 0; ii < 4; ++ii) {
        float4 o; float v;
        v = fmaxf(acc[ii][0], 0.f); o.x = v * rsqrtf(v * v + EPSN);
        v = fmaxf(acc[ii][1], 0.f); o.y = v * rsqrtf(v * v + EPSN);
        v = fmaxf(acc[ii][2], 0.f); o.z = v * rsqrtf(v * v + EPSN);
        v = fmaxf(acc[ii][3], 0.f); o.w = v * rsqrtf(v * v + EPSN);
        *(float4*)&cb[(size_t)(i0 + ty * 4 + ii) * 1024 + j0 + tx * 4] = o;
    }
}

// ---------------- mutual matching ----------------
__global__ __launch_bounds__(256) void rowmax_k(const float* __restrict__ c,
                                                float* __restrict__ maxR)
{
    int b = blockIdx.y, i = blockIdx.x, tid = threadIdx.x;
    const float* row = c + ((size_t)b << 20) + ((size_t)i << 10);
    float m = fmaxf(fmaxf(row[tid], row[tid + 256]), fmaxf(row[tid + 512], row[tid + 768]));
    #pragma unroll
    for (int off = 32; off; off >>= 1) m = fmaxf(m, __shfl_down(m, off, 64));
    __shared__ float sred[4];
    if ((tid & 63) == 0) sred[tid >> 6] = m;
    __syncthreads();
    if (tid == 0)
        maxR[b * 1024 + i] = fmaxf(fmaxf(sred[0], sred[1]), fmaxf(sred[2], sred[3]));
}

__global__ __launch_bounds__(256) void colmax_k(const float* __restrict__ c,
                                                float* __restrict__ maxC)
{
    int j = blockIdx.x * 256 + threadIdx.x;
    int r0 = blockIdx.y * 128;
    int b = blockIdx.z;
    const float* cb = c + ((size_t)b << 20);
    float m = 0.f;
    for (int r = 0; r < 128; ++r) m = fmaxf(m, cb[(size_t)(r0 + r) * 1024 + j]);
    atomicMax((int*)&maxC[b * 1024 + j], __float_as_int(m));
}

__global__ __launch_bounds__(256) void mmapply_k(float* __restrict__ c,
                                                 const float* __restrict__ maxR,
                                                 const float* __restrict__ maxC)
{
    int e4 = blockIdx.x * 256 + threadIdx.x;
    int e = e4 * 4;
    int b = e >> 20, i = (e >> 10) & 1023, j0 = e & 1023;
    float4 v = ((float4*)c)[e4];
    float ra = 1.f / (maxR[b * 1024 + i] + EPSM);
    float4 mb = ((const float4*)maxC)[(b * 1024 + j0) >> 2];
    float4 o;
    o.x = v.x * v.x * v.x * ra / (mb.x + EPSM);
    o.y = v.y * v.y * v.y * ra / (mb.y + EPSM);
    o.z = v.z * v.z * v.z * ra / (mb.z + EPSM);
    o.w = v.w * v.w * v.w * ra / (mb.w + EPSM);
    ((float4*)c)[e4] = o;
}

// ---------------- f32 weight pack (layer 1): [CO][CI][81] -> [CI][27][WS] ------
template <int CI, int CO>
__global__ void packw_k(const float* __restrict__ w, float* __restrict__ dst, int perm)
{
    constexpr int WS = (3 * CO + 3) & ~3;
    int idx = blockIdx.x * 256 + threadIdx.x;
    if (idx >= CI * 27 * WS) return;
    int ci = idx / (27 * WS);
    int rem = idx - ci * 27 * WS;
    int d123 = rem / WS;
    int slot = rem - d123 * WS;
    float v = 0.f;
    if (slot < 3 * CO) {
        int d4 = slot / CO, co = slot - d4 * CO;
        int t = d123 * 3 + d4;
        int d1 = t / 27, r2 = t % 27;
        int d2 = r2 / 9, r3 = r2 % 9;
        int d3 = r3 / 3, dd4 = r3 % 3;
        int st = perm ? (d3 * 27 + dd4 * 9 + d1 * 3 + d2) : t;
        v = w[(co * CI + ci) * 81 + st];
    }
    dst[idx] = v;
}

// ---------------- mfma weight pack (layer 2): [10][10][81] -> [81][co16][k16] f16
__global__ void packwm_k(const float* __restrict__ w, unsigned short* __restrict__ dst,
                         int perm)
{
    int idx = blockIdx.x * 256 + threadIdx.x;   // 81*256 = 20736
    if (idx >= 20736) return;
    int tap = idx >> 8;
    int co  = (idx >> 4) & 15;
    int k   = idx & 15;
    float v = 0.f;
    if (co < 10 && k < 10) {
        int d1 = tap / 27, r2 = tap % 27;
        int d2 = r2 / 9, r3 = r2 % 9;
        int d3 = r3 / 3, d4 = r3 % 3;
        int st = perm ? (d3 * 27 + d4 * 9 + d1 * 3 + d2) : tap;
        v = w[(co * 10 + k) * 81 + st];
    }
    union { __fp16 h; unsigned short u; } cv;
    cv.h = (__fp16)v;
    dst[idx] = cv.u;
}

// ---------------- f16-pair weight pack (layer 3): [CO][2*CIP][81] -> [CIP][27][WS]
template <int CIP, int CO>
__global__ void packw2_k(const float* __restrict__ w, unsigned* __restrict__ dst, int perm)
{
    constexpr int WS = (3 * CO + 3) & ~3;
    int idx = blockIdx.x * 256 + threadIdx.x;
    if (idx >= CIP * 27 * WS) return;
    int pp = idx / (27 * WS);
    int rem = idx - pp * 27 * WS;
    int d123 = rem / WS;
    int slot = rem - d123 * WS;
    unsigned v = 0u;
    if (slot < 3 * CO) {
        int d4 = slot / CO, co = slot - d4 * CO;
        int t = d123 * 3 + d4;
        int d1 = t / 27, r2 = t % 27;
        int d2 = r2 / 9, r3 = r2 % 9;
        int d3 = r3 / 3, dd4 = r3 % 3;
        int st = perm ? (d3 * 27 + dd4 * 9 + d1 * 3 + d2) : t;
        float f0 = w[(co * 2 * CIP + 2 * pp) * 81 + st];
        float f1 = w[(co * 2 * CIP + 2 * pp + 1) * 81 + st];
        v = pkh2(f0, f1);
    }
    dst[idx] = v;
}

// ---------------- f32 4D conv (layer 1, CI=1), optional packed-f16-pair output --
template <int CI, int CO, bool ADD, bool PACK>
__global__ __launch_bounds__(256, 4) void conv4d_k(const float* __restrict__ x,
                                                   const float* __restrict__ wp,
                                                   const float* __restrict__ bias,
                                                   float* __restrict__ y)
{
    constexpr int WS = (3 * CO + 3) & ~3;
    constexpr int NW4 = WS / 4;
    constexpr int SLAB = 34 * 35;
    __shared__ float tile[3 * SLAB];

    int tid = threadIdx.x;
    int f1 = blockIdx.x >> 5, f2 = blockIdx.x & 31;
    int q = tid & 7, yy = tid >> 3;
    int x0 = q << 2;

    for (int e = tid; e < 3 * SLAB; e += 256) tile[e] = 0.f;

    float acc[CO][4];
    #pragma unroll
    for (int co = 0; co < CO; ++co) {
        float bv = bias[co];
        acc[co][0] = bv; acc[co][1] = bv; acc[co][2] = bv; acc[co][3] = bv;
    }

    float bufA[WS], bufB[WS];

#define TAP(U, WB, WN, PF) do {                                               \
        constexpr int u_ = (U);                                               \
        const float* rowb_ = &tile[(u_/3)*SLAB + (yy + u_%3)*35 + x0];        \
        float xs_[6];                                                         \
        _Pragma("unroll") for (int j = 0; j < 6; ++j) xs_[j] = rowb_[j];      \
        if (PF) {                                                             \
            _Pragma("unroll") for (int k = 0; k < NW4; ++k)                   \
                *(float4*)&WN[k*4] =                                          \
                    ((const float4*)(wphase + (u_+1)*WS))[k];                 \
        }                                                                     \
        _Pragma("unroll") for (int d4 = 0; d4 < 3; ++d4)                      \
        _Pragma("unroll") for (int co = 0; co < CO; ++co) {                   \
            float wf_ = WB[d4*CO + co];                                       \
            _Pragma("unroll") for (int p = 0; p < 4; ++p)                     \
                acc[co][p] = fmaf(xs_[p + d4], wf_, acc[co][p]);              \
        }                                                                     \
    } while (0)

    #pragma unroll 1
    for (int ci = 0; ci < CI; ++ci) {
        const float* wci = wp + ci * 27 * WS;
        #pragma unroll 1
        for (int d1 = 0; d1 < 3; ++d1) {
            int g1 = f1 + d1 - 1;
            bool g1ok = (unsigned)g1 < 32u;
            const float* wphase = wci + d1 * 9 * WS;
            __syncthreads();
            #pragma unroll
            for (int k = 0; k < NW4; ++k)
                *(float4*)&bufA[k*4] = ((const float4*)wphase)[k];
            #pragma unroll
            for (int it = 0; it < 3; ++it) {
                int e = tid + it * 256;
                int s2 = e >> 8, rr = (e >> 3) & 31, qq = e & 7;
                int g2 = f2 + s2 - 1;
                float4 v = {0.f, 0.f, 0.f, 0.f};
                if (g1ok & ((unsigned)g2 < 32u))
                    v = *(const float4*)&x[((size_t)ci << 20) +
                        ((size_t)((g1 << 5) + g2) << 10) + (rr << 5) + (qq << 2)];
                float* t = &tile[s2 * SLAB + (rr + 1) * 35 + 1 + (qq << 2)];
                t[0] = v.x; t[1] = v.y; t[2] = v.z; t[3] = v.w;
            }
            __syncthreads();

            TAP(0, bufA, bufB, true);
            TAP(1, bufB, bufA, true);
            TAP(2, bufA, bufB, true);
            TAP(3, bufB, bufA, true);
            TAP(4, bufA, bufB, true);
            TAP(5, bufB, bufA, true);
            TAP(6, bufA, bufB, true);
            TAP(7, bufB, bufA, true);
            TAP(8, bufA, bufB, false);
        }
    }
#undef TAP

    size_t obase = ((size_t)(f1 * 32 + f2) << 10) + yy * 32 + x0;
    if (PACK) {
        // packed f16 ci-pair output: [CO/2][1M] u32
        unsigned* ypu = (unsigned*)y;
        #pragma unroll
        for (int c = 0; c < CO / 2; ++c) {
            uint4 o;
            o.x = pkh2(fmaxf(acc[2*c][0], 0.f), fmaxf(acc[2*c+1][0], 0.f));
            o.y = pkh2(fmaxf(acc[2*c][1], 0.f), fmaxf(acc[2*c+1][1], 0.f));
            o.z = pkh2(fmaxf(acc[2*c][2], 0.f), fmaxf(acc[2*c+1][2], 0.f));
            o.w = pkh2(fmaxf(acc[2*c][3], 0.f), fmaxf(acc[2*c+1][3], 0.f));
            *(uint4*)&ypu[(size_t)c * 1048576 + obase] = o;
        }
    } else {
        #pragma unroll
        for (int co = 0; co < CO; ++co) {
            float4 o;
            o.x = fmaxf(acc[co][0], 0.f);
            o.y = fmaxf(acc[co][1], 0.f);
            o.z = fmaxf(acc[co][2], 0.f);
            o.w = fmaxf(acc[co][3], 0.f);
            float* yp = y + ((size_t)co << 20) + obase;
            if (ADD) {
                float4 prev = *(const float4*)yp;
                o.x += prev.x; o.y += prev.y; o.z += prev.z; o.w += prev.w;
            }
            *(float4*)yp = o;
        }
    }
}

// ---------------- MFMA 4D conv (layer 2: CI=10, CO=10) ------------------------
// xp: [5][1M] u32 (f16 ci-pairs), wm: [81][co16][k16] f16, yp: [5][1M] u32 pairs
// XCD-chunked swizzle: chunk = bx&7 (XCD via %8 round-robin) owns f1 in
// [4*chunk, 4*chunk+3] -> halo working set (~1.9MB) stays in that XCD's L2.
// LDS x-tile ci-interleaved: [s2][row][col][9 u32] (18 f16, pads zero).
// Epilogue: fragments -> padded LDS (stride 33) -> dense uint4 stores.
__global__ __launch_bounds__(256, 4) void conv4dm_k(const unsigned* __restrict__ xp,
                                                    const unsigned short* __restrict__ wm,
                                                    const float* __restrict__ bias,
                                                    unsigned* __restrict__ yp)
{
    __shared__ unsigned tile[3 * 10 * 34 * 9];   // 9180 u32 = 36720 B

    int tid = threadIdx.x;
    int bx = blockIdx.x;
    int chunk  = bx & 7;          // XCD id (round-robin heuristic)
    int within = bx >> 3;         // 0..511, ascending per XCD
    int f1 = (chunk << 2) | (within >> 7);
    int f2 = (within >> 2) & 31;
    int q  = within & 3;

    int l  = tid & 63;
    int wv = tid >> 6;        // wave 0..3
    int sl = l & 15;          // A: co-row; B/D: spatial col
    int g  = l >> 4;          // k-group / D row-group

    for (int e = tid; e < 9180; e += 256) tile[e] = 0u;

    f32x4 bv;
    #pragma unroll
    for (int e = 0; e < 4; ++e) {
        int co = 4 * g + e;
        bv[e] = (co < 10) ? bias[co] : 0.f;
    }
    f32x4 acc0 = bv, acc1 = bv, acc2 = bv, acc3 = bv;

    int qbase = q * 8;

    #pragma unroll 1
    for (int d1 = 0; d1 < 3; ++d1) {
        int g1 = f1 + d1 - 1;
        bool g1ok = (unsigned)g1 < 32u;
        __syncthreads();   // previous-phase tile consumers done

        // prefetch this phase's 27 A-fragments (w[tap][co=sl][k=4g..4g+3])
        uint2 aw[27];
        #pragma unroll
        for (int t27 = 0; t27 < 27; ++t27) {
            int tap = d1 * 27 + t27;
            aw[t27] = *(const uint2*)&wm[(tap << 8) + (sl << 4) + (g << 2)];
        }

        // stage: 240 groups = 3 slabs x 10 rows x 8 col-quads; 5 uint4 each
        if (tid < 240) {
            int k  = tid & 7;
            int rg = tid >> 3;          // 0..29
            int r  = rg % 10;
            int s2 = rg / 10;
            int c  = 1 + (k << 2);
            int g2 = f2 + s2 - 1;
            int g3 = qbase + r - 1;
            uint4 v0 = {0,0,0,0}, v1 = {0,0,0,0}, v2 = {0,0,0,0},
                  v3 = {0,0,0,0}, v4 = {0,0,0,0};
            if (g1ok & ((unsigned)g2 < 32u) & ((unsigned)g3 < 32u)) {
                size_t off = ((size_t)((g1 << 5) + g2) << 10) + (g3 << 5) + (c - 1);
                v0 = *(const uint4*)&xp[off];
                v1 = *(const uint4*)&xp[off + 1048576];
                v2 = *(const uint4*)&xp[off + 2097152];
                v3 = *(const uint4*)&xp[off + 3145728];
                v4 = *(const uint4*)&xp[off + 4194304];
            }
            unsigned* tb = &tile[((s2 * 10 + r) * 34 + c) * 9];
            tb[0] = v0.x; tb[9]  = v0.y; tb[18] = v0.z; tb[27] = v0.w;
            tb[1] = v1.x; tb[10] = v1.y; tb[19] = v1.z; tb[28] = v1.w;
            tb[2] = v2.x; tb[11] = v2.y; tb[20] = v2.z; tb[29] = v2.w;
            tb[3] = v3.x; tb[12] = v3.y; tb[21] = v3.z; tb[30] = v3.w;
            tb[4] = v4.x; tb[13] = v4.y; tb[22] = v4.z; tb[31] = v4.w;
        }
        __syncthreads();

        // compute: 27 taps x 4 tiles (2 rows x 2 col-halves per wave)
        int tb0 = ((wv * 2 + 0) * 34 + sl) * 9 + (g << 1);   // row rt=2wv,  ch=0
        #pragma unroll
        for (int d2 = 0; d2 < 3; ++d2)
        #pragma unroll
        for (int d3 = 0; d3 < 3; ++d3)
        #pragma unroll
        for (int d4 = 0; d4 < 3; ++d4) {
            int t27 = d2 * 9 + d3 * 3 + d4;
            union { uint2 u; f16x4 h; } A; A.u = aw[t27];
            int tapoff = ((d2 * 10 + d3) * 34 + d4) * 9;     // compile-time per tap
            const unsigned* bp = &tile[tb0 + tapoff];
            union { uint2 u; f16x4 h; } B;
            B.u.x = bp[0];           B.u.y = bp[1];
            acc0 = MFMA16(A.h, B.h, acc0);
            B.u.x = bp[16 * 9];      B.u.y = bp[16 * 9 + 1];       // ch=1
            acc1 = MFMA16(A.h, B.h, acc1);
            B.u.x = bp[34 * 9];      B.u.y = bp[34 * 9 + 1];       // rt=2wv+1
            acc2 = MFMA16(A.h, B.h, acc2);
            B.u.x = bp[50 * 9];      B.u.y = bp[50 * 9 + 1];       // rt+1, ch=1
            acc3 = MFMA16(A.h, B.h, acc3);
        }
    }

    // epilogue: relu + pack co-pairs into padded LDS, then dense uint4 stores.
    // LDS layout: eo[(p*8 + row)*33 + col], p=ci-pair 0..4, row 0..7, col 0..31
    __syncthreads();   // done reading tile as input
#define EPST(ACC, RT, CH) do {                                                \
        int row_ = (RT);                                                      \
        int col_ = (CH) * 16 + sl;                                            \
        float r0 = fmaxf((ACC)[0], 0.f), r1 = fmaxf((ACC)[1], 0.f);           \
        float r2 = fmaxf((ACC)[2], 0.f), r3 = fmaxf((ACC)[3], 0.f);           \
        if (g < 2) {                                                          \
            tile[((2*g)     * 8 + row_) * 33 + col_] = pkh2(r0, r1);          \
            tile[((2*g + 1) * 8 + row_) * 33 + col_] = pkh2(r2, r3);          \
        } else if (g == 2) {                                                  \
            tile[(4 * 8 + row_) * 33 + col_] = pkh2(r0, r1);                  \
        }                                                                     \
    } while (0)
    EPST(acc0, wv * 2 + 0, 0);
    EPST(acc1, wv * 2 + 0, 1);
    EPST(acc2, wv * 2 + 1, 0);
    EPST(acc3, wv * 2 + 1, 1);
#undef EPST
    __syncthreads();

    size_t pbase = ((size_t)((f1 << 5) + f2) << 10);
    #pragma unroll
    for (int u = tid; u < 320; u += 256) {
        int p   = u >> 6;
        int rem = u & 63;
        int row = rem >> 3;
        int cg  = rem & 7;
        const unsigned* src = &tile[(p * 8 + row) * 33 + (cg << 2)];
        uint4 v;
        v.x = src[0]; v.y = src[1]; v.z = src[2]; v.w = src[3];
        *(uint4*)&yp[(size_t)p * 1048576 + pbase +
                     ((size_t)(qbase + row) << 5) + (cg << 2)] = v;
    }
}

// ---------------- f16-pair 4D conv (layer 3): packed-pair input, dot2 ---------
// xp: [CIP][1M] u32 (f16 ci-pairs), wp: [CIP][27][WS] u32 pairs, y: [CO][1M] f32
template <int CIP, int CO, bool ADD>
__global__ __launch_bounds__(256, 4) void conv4dp_k(const unsigned* __restrict__ xp,
                                                    const unsigned* __restrict__ wp,
                                                    const float* __restrict__ bias,
                                                    float* __restrict__ y)
{
    constexpr int WS = (3 * CO + 3) & ~3;
    constexpr int NW4 = WS / 4;
    constexpr int SLAB = 34 * 35;
    __shared__ unsigned tile[3 * SLAB];

    int tid = threadIdx.x;
    int f1 = blockIdx.x >> 5, f2 = blockIdx.x & 31;
    int q = tid & 7, yy = tid >> 3;
    int x0 = q << 2;

    for (int e = tid; e < 3 * SLAB; e += 256) tile[e] = 0u;

    float acc[CO][4];
    #pragma unroll
    for (int co = 0; co < CO; ++co) {
        float bvv = bias[co];
        acc[co][0] = bvv; acc[co][1] = bvv; acc[co][2] = bvv; acc[co][3] = bvv;
    }

    unsigned bufA[WS], bufB[WS];

#define TAPP(U, WB, WN, PF) do {                                              \
        constexpr int u_ = (U);                                               \
        const unsigned* rowb_ = &tile[(u_/3)*SLAB + (yy + u_%3)*35 + x0];     \
        unsigned xs_[6];                                                      \
        _Pragma("unroll") for (int j = 0; j < 6; ++j) xs_[j] = rowb_[j];      \
        if (PF) {                                                             \
            _Pragma("unroll") for (int k = 0; k < NW4; ++k)                   \
                *(uint4*)&WN[k*4] =                                           \
                    ((const uint4*)(wphase + (u_+1)*WS))[k];                  \
        }                                                                     \
        _Pragma("unroll") for (int d4 = 0; d4 < 3; ++d4)                      \
        _Pragma("unroll") for (int co = 0; co < CO; ++co) {                   \
            unsigned wf_ = WB[d4*CO + co];                                    \
            _Pragma("unroll") for (int p = 0; p < 4; ++p)                     \
                acc[co][p] = dot2f(xs_[p + d4], wf_, acc[co][p]);             \
        }                                                                     \
    } while (0)

    #pragma unroll 1
    for (int pp = 0; pp < CIP; ++pp) {
        const unsigned* wci = wp + pp * 27 * WS;
        #pragma unroll 1
        for (int d1 = 0; d1 < 3; ++d1) {
            int g1 = f1 + d1 - 1;
            bool g1ok = (unsigned)g1 < 32u;
            const unsigned* wphase = wci + d1 * 9 * WS;
            __syncthreads();
            #pragma unroll
            for (int k = 0; k < NW4; ++k)
                *(uint4*)&bufA[k*4] = ((const uint4*)wphase)[k];
            #pragma unroll
            for (int it = 0; it < 3; ++it) {
                int e = tid + it * 256;
                int s2 = e >> 8, rr = (e >> 3) & 31, qq = e & 7;
                int g2 = f2 + s2 - 1;
                uint4 v = {0u, 0u, 0u, 0u};
                if (g1ok & ((unsigned)g2 < 32u))
                    v = *(const uint4*)&xp[((size_t)pp << 20) +
                        ((size_t)((g1 << 5) + g2) << 10) + (rr << 5) + (qq << 2)];
                unsigned* t = &tile[s2 * SLAB + (rr + 1) * 35 + 1 + (qq << 2)];
                t[0] = v.x; t[1] = v.y; t[2] = v.z; t[3] = v.w;
            }
            __syncthreads();

            TAPP(0, bufA, bufB, true);
            TAPP(1, bufB, bufA, true);
            TAPP(2, bufA, bufB, true);
            TAPP(3, bufB, bufA, true);
            TAPP(4, bufA, bufB, true);
            TAPP(5, bufB, bufA, true);
            TAPP(6, bufA, bufB, true);
            TAPP(7, bufB, bufA, true);
            TAPP(8, bufA, bufB, false);
        }
    }
#undef TAPP

    size_t obase = ((size_t)(f1 * 32 + f2) << 10) + yy * 32 + x0;
    #pragma unroll
    for (int co = 0; co < CO; ++co) {
        float4 o;
        o.x = fmaxf(acc[co][0], 0.f);
        o.y = fmaxf(acc[co][1], 0.f);
        o.z = fmaxf(acc[co][2], 0.f);
        o.w = fmaxf(acc[co][3], 0.f);
        float* ypt = y + ((size_t)co << 20) + obase;
        if (ADD) {
            float4 prev = *(const float4*)ypt;
            o.x += prev.x; o.y += prev.y; o.z += prev.z; o.w += prev.w;
        }
        *(float4*)ypt = o;
    }
}

extern "C" void kernel_launch(void* const* d_in, const int* in_sizes, int n_in,
                              void* d_out, int out_size, void* d_ws, size_t ws_size,
                              hipStream_t stream)
{
    (void)in_sizes; (void)n_in; (void)out_size; (void)ws_size;
    const float* fA = (const float*)d_in[0];
    const float* fB = (const float*)d_in[1];
    const float* w1 = (const float*)d_in[2];
    const float* b1 = (const float*)d_in[3];
    const float* w2 = (const float*)d_in[4];
    const float* b2 = (const float*)d_in[5];
    const float* w3 = (const float*)d_in[6];
    const float* b3 = (const float*)d_in[7];
    float* out = (float*)d_out;
    float* ws = (float*)d_ws;

    size_t o = 0;
    float* invA = ws + o; o += 4096;
    float* invB = ws + o; o += 4096;
    float* maxR = ws + o; o += 4096;
    float* maxC = ws + o; o += 4096;
    float* pw1  = ws + o; o += 2048;                       // 2 x [1][27][32] f32
    unsigned short* wm2 = (unsigned short*)(ws + o); o += 20736;  // 2 x 20736 ushort
    unsigned* pw3 = (unsigned*)(ws + o); o += 1080;        // 2 x [5][27][4] u32
    float* corr = ws + o; o += 4194304;                    // [4][1024][1024]
    unsigned* t1p = (unsigned*)(ws + o); o += 5242880;     // [5][1M] u32 pairs
    unsigned* t2p = (unsigned*)(ws + o); o += 5242880;     // [5][1M] u32 pairs

    invnorm_k<<<64, 256, 0, stream>>>(fA, invA);
    invnorm_k<<<64, 256, 0, stream>>>(fB, invB);
    corr_k<<<dim3(16, 16, 4), 256, 0, stream>>>(fA, fB, invA, invB, corr);

    // mutual matching #1 (in place on corr)
    rowmax_k<<<dim3(1024, 4), 256, 0, stream>>>(corr, maxR);
    (void)hipMemsetAsync(maxC, 0, 4096 * sizeof(float), stream);
    colmax_k<<<dim3(4, 8, 4), 256, 0, stream>>>(corr, maxC);
    mmapply_k<<<4096, 256, 0, stream>>>(corr, maxR, maxC);

    // packed weights (A = normal, B = kernel-axis-permuted symmetric branch)
    packw_k<1, 10><<<4, 256, 0, stream>>>(w1, pw1, 0);
    packw_k<1, 10><<<4, 256, 0, stream>>>(w1, pw1 + 864, 1);
    packwm_k<<<81, 256, 0, stream>>>(w2, wm2, 0);
    packwm_k<<<81, 256, 0, stream>>>(w2, wm2 + 20736, 1);
    packw2_k<5, 1><<<3, 256, 0, stream>>>(w3, pw3, 0);
    packw2_k<5, 1><<<3, 256, 0, stream>>>(w3, pw3 + 540, 1);

    for (int b = 0; b < 4; ++b) {
        const float* xb = corr + (size_t)b * 1048576;
        float* ob = out + (size_t)b * 1048576;
        conv4d_k<1, 10, false, true><<<1024, 256, 0, stream>>>(xb, pw1, b1, (float*)t1p);
        conv4dm_k<<<4096, 256, 0, stream>>>(t1p, wm2, b2, t2p);
        conv4dp_k<5, 1, false><<<1024, 256, 0, stream>>>(t2p, pw3, b3, ob);
        conv4d_k<1, 10, false, true><<<1024, 256, 0, stream>>>(xb, pw1 + 864, b1, (float*)t1p);
        conv4dm_k<<<4096, 256, 0, stream>>>(t1p, wm2 + 20736, b2, t2p);
        conv4dp_k<5, 1, true ><<<1024, 256, 0, stream>>>(t2p, pw3 + 540, b3, ob);
    }

    // mutual matching #2 (in place on out)
    rowmax_k<<<dim3(1024, 4), 256, 0, stream>>>(out, maxR);
    (void)hipMemsetAsync(maxC, 0, 4096 * sizeof(float), stream);
    colmax_k<<<dim3(4, 8, 4), 256, 0, stream>>>(out, maxC);
    mmapply_k<<<4096, 256, 0, stream>>>(out, maxR, maxC);
}